// Round 1
// baseline (611.247 us; speedup 1.0000x reference)
//
#include <hip/hip_runtime.h>
#include <math.h>

#define DM   2048
#define NH   16
#define DH   128
#define SEQ  2048
#define NB   2

typedef _Float16 f16x8 __attribute__((ext_vector_type(8)));
typedef float    f32x4 __attribute__((ext_vector_type(4)));

#define MFMA(a, b, c) __builtin_amdgcn_mfma_f32_16x16x32_f16((a), (b), (c), 0, 0, 0)

// -------------------- RoPE sin/cos table: [SEQ][64] each --------------------
__global__ void k_sincos(float* __restrict__ ct, float* __restrict__ st) {
    int idx = blockIdx.x * blockDim.x + threadIdx.x;   // SEQ*64 = 131072
    int p = idx >> 6, i = idx & 63;
    // freq = 10000^(i/64); angle = p / freq
    float inv_freq = expf(-(float)i * (9.210340371976184f / 64.0f));
    float a = (float)p * inv_freq;
    float s, c;
    sincosf(a, &s, &c);
    ct[idx] = c;
    st[idx] = s;
}

// ---------- tiled transpose fp32 [batch][R][C] -> fp16 [batch][C][R] ----------
__global__ void k_transpose(const float* __restrict__ in, _Float16* __restrict__ out,
                            int R, int C) {
    __shared__ float tile[32][33];
    size_t base = (size_t)blockIdx.z * (size_t)R * (size_t)C;
    int c0 = blockIdx.x * 32, r0 = blockIdx.y * 32;
    int tx = threadIdx.x, ty = threadIdx.y;   // 32 x 8
#pragma unroll
    for (int i = 0; i < 4; i++)
        tile[ty + i * 8][tx] = in[base + (size_t)(r0 + ty + i * 8) * C + c0 + tx];
    __syncthreads();
#pragma unroll
    for (int i = 0; i < 4; i++)
        out[base + (size_t)(c0 + ty + i * 8) * R + r0 + tx] = (_Float16)tile[tx][ty + i * 8];
}

// -------------------- QKV projection + bias + RoPE + scale --------------------
// z=0: Q (rope+scale), z=1: K (rope), z=2: V (written transposed [B,H,D,S])
__global__ __launch_bounds__(256)
void k_proj(const float* __restrict__ Xq, const float* __restrict__ Xk, const float* __restrict__ Xv,
            const _Float16* __restrict__ WTq, const _Float16* __restrict__ WTk, const _Float16* __restrict__ WTv,
            const float* __restrict__ bQ, const float* __restrict__ bK, const float* __restrict__ bV,
            _Float16* __restrict__ q_out, _Float16* __restrict__ k_out, _Float16* __restrict__ vt_out,
            const float* __restrict__ ct, const float* __restrict__ st) {
    __shared__ __align__(16) _Float16 At[128][72];
    __shared__ __align__(16) _Float16 Bt[128][72];

    const int z = blockIdx.z;
    const float* X = (z == 0) ? Xq : (z == 1) ? Xk : Xv;
    const _Float16* WT = (z == 0) ? WTq : (z == 1) ? WTk : WTv;
    const float* bias = (z == 0) ? bQ : (z == 1) ? bK : bV;
    const int h  = blockIdx.y;
    const int m0 = blockIdx.x * 128;
    const int tid = threadIdx.x;
    const int w = tid >> 6, lane = tid & 63, lg = lane >> 4, lr = lane & 15;

    const _Float16* WTh = WT + (size_t)h * DH * DM;

    f32x4 acc[2][8] = {};

    for (int k0 = 0; k0 < DM; k0 += 64) {
        __syncthreads();
        // A tile: 128 rows x 64 k, fp32 -> fp16
#pragma unroll
        for (int i = 0; i < 4; i++) {
            int cid = i * 256 + tid;
            int row = cid >> 3, c8 = (cid & 7) * 8;
            const float4* p = (const float4*)(X + (size_t)(m0 + row) * DM + k0 + c8);
            float4 u = p[0], v = p[1];
            f16x8 pk;
            pk[0] = (_Float16)u.x; pk[1] = (_Float16)u.y; pk[2] = (_Float16)u.z; pk[3] = (_Float16)u.w;
            pk[4] = (_Float16)v.x; pk[5] = (_Float16)v.y; pk[6] = (_Float16)v.z; pk[7] = (_Float16)v.w;
            *(f16x8*)&At[row][c8] = pk;
        }
        // B^T tile: 128 cols(e) x 64 k (already fp16, pre-transposed)
#pragma unroll
        for (int i = 0; i < 4; i++) {
            int cid = i * 256 + tid;
            int c = cid >> 3, k8 = (cid & 7) * 8;
            *(f16x8*)&Bt[c][k8] = *(const f16x8*)(WTh + (size_t)c * DM + k0 + k8);
        }
        __syncthreads();
#pragma unroll
        for (int kk = 0; kk < 2; kk++) {
            f16x8 a[2], b[8];
#pragma unroll
            for (int m = 0; m < 2; m++) a[m] = *(const f16x8*)&At[w * 32 + m * 16 + lr][kk * 32 + lg * 8];
#pragma unroll
            for (int n = 0; n < 8; n++) b[n] = *(const f16x8*)&Bt[n * 16 + lr][kk * 32 + lg * 8];
#pragma unroll
            for (int m = 0; m < 2; m++)
#pragma unroll
                for (int n = 0; n < 8; n++)
                    acc[m][n] = MFMA(a[m], b[n], acc[m][n]);
        }
    }

    float bias_v[8];
#pragma unroll
    for (int n = 0; n < 8; n++) bias_v[n] = bias[h * DH + n * 16 + lr];

    const int bb = m0 >> 11;           // batch index
    const int s_base = (m0 & 2047) + w * 32;

    if (z < 2) {
        _Float16* outp = (z == 0) ? q_out : k_out;
        const float scale = (z == 0) ? 0.08838834764831845f : 1.0f;  // 1/sqrt(128)
#pragma unroll
        for (int m = 0; m < 2; m++) {
#pragma unroll
            for (int r = 0; r < 4; r++) {
                int s = s_base + m * 16 + lg * 4 + r;
                size_t rowbase = ((size_t)(bb * NH + h) * SEQ + s) * DH;
#pragma unroll
                for (int n = 0; n < 4; n++) {
                    int c = n * 16 + lr;                 // < 64
                    float cv = ct[s * 64 + c];
                    float sv = st[s * 64 + c];
                    float x0 = acc[m][n][r]     + bias_v[n];
                    float x1 = acc[m][n + 4][r] + bias_v[n + 4];
                    float y0 = (x0 * cv - x1 * sv) * scale;
                    float y1 = (x1 * cv + x0 * sv) * scale;
                    outp[rowbase + c]      = (_Float16)y0;
                    outp[rowbase + c + 64] = (_Float16)y1;
                }
            }
        }
    } else {
#pragma unroll
        for (int m = 0; m < 2; m++)
#pragma unroll
            for (int r = 0; r < 4; r++) {
                int s = s_base + m * 16 + lg * 4 + r;
#pragma unroll
                for (int n = 0; n < 8; n++) {
                    int d = n * 16 + lr;
                    vt_out[((size_t)(bb * NH + h) * DH + d) * SEQ + s] =
                        (_Float16)(acc[m][n][r] + bias_v[n]);
                }
            }
    }
}

// -------------------- causal flash attention --------------------
// q pre-scaled by 1/sqrt(DH). q,k: [B,H,S,D]; v: [B,H,D,S]; z out: [B,S,H,D]
__global__ __launch_bounds__(256)
void k_attn(const _Float16* __restrict__ q_ws, const _Float16* __restrict__ k_ws,
            const _Float16* __restrict__ vt_ws, _Float16* __restrict__ z_ws) {
    __shared__ __align__(16) _Float16 Qs[64][136];
    __shared__ __align__(16) _Float16 Ks[64][136];
    __shared__ __align__(16) _Float16 Vs[128][72];
    __shared__ __align__(16) _Float16 Ps[4][16][72];

    const int bh = blockIdx.y;          // b*NH + h
    const int qt = blockIdx.x * 64;
    const int tid = threadIdx.x;
    const int w = tid >> 6, lane = tid & 63, lg = lane >> 4, lr = lane & 15;

    const _Float16* Qg = q_ws + (size_t)bh * SEQ * DH;
    const _Float16* Kg = k_ws + (size_t)bh * SEQ * DH;
    const _Float16* Vg = vt_ws + (size_t)bh * DH * SEQ;

#pragma unroll
    for (int i = 0; i < 4; i++) {
        int cid = i * 256 + tid;
        int row = cid >> 4, c8 = (cid & 15) * 8;
        *(f16x8*)&Qs[row][c8] = *(const f16x8*)(Qg + (size_t)(qt + row) * DH + c8);
    }

    f32x4 accO[8] = {};
    float m_r[4] = {-1e30f, -1e30f, -1e30f, -1e30f};
    float l_r[4] = {0.f, 0.f, 0.f, 0.f};

    const int ntile = blockIdx.x + 1;
    for (int t = 0; t < ntile; t++) {
        const int kv0 = t * 64;
        __syncthreads();
#pragma unroll
        for (int i = 0; i < 4; i++) {
            int cid = i * 256 + tid;
            int row = cid >> 4, c8 = (cid & 15) * 8;
            *(f16x8*)&Ks[row][c8] = *(const f16x8*)(Kg + (size_t)(kv0 + row) * DH + c8);
        }
#pragma unroll
        for (int i = 0; i < 4; i++) {
            int cid = i * 256 + tid;
            int d = cid >> 3, c8 = (cid & 7) * 8;
            *(f16x8*)&Vs[d][c8] = *(const f16x8*)(Vg + (size_t)d * SEQ + kv0 + c8);
        }
        __syncthreads();

        // S = Q K^T  (wave: 16 q-rows x 64 kv)
        f32x4 sc[4] = {};
#pragma unroll
        for (int kk = 0; kk < 4; kk++) {
            f16x8 aq = *(const f16x8*)&Qs[w * 16 + lr][kk * 32 + lg * 8];
#pragma unroll
            for (int n = 0; n < 4; n++) {
                f16x8 bk = *(const f16x8*)&Ks[n * 16 + lr][kk * 32 + lg * 8];
                sc[n] = MFMA(aq, bk, sc[n]);
            }
        }
        // causal mask
#pragma unroll
        for (int n = 0; n < 4; n++) {
            int kvc = kv0 + n * 16 + lr;
#pragma unroll
            for (int r = 0; r < 4; r++) {
                int qr = qt + w * 16 + lg * 4 + r;
                if (kvc > qr) sc[n][r] = -1e30f;
            }
        }
        // online softmax (row reductions over 16-lane groups)
        float mt[4];
#pragma unroll
        for (int r = 0; r < 4; r++)
            mt[r] = fmaxf(fmaxf(sc[0][r], sc[1][r]), fmaxf(sc[2][r], sc[3][r]));
#pragma unroll
        for (int off = 1; off < 16; off <<= 1)
#pragma unroll
            for (int r = 0; r < 4; r++) mt[r] = fmaxf(mt[r], __shfl_xor(mt[r], off));
        float al[4];
#pragma unroll
        for (int r = 0; r < 4; r++) {
            float mn = fmaxf(m_r[r], mt[r]);
            al[r] = __expf(m_r[r] - mn);
            m_r[r] = mn;
        }
        float ps[4] = {0.f, 0.f, 0.f, 0.f};
#pragma unroll
        for (int n = 0; n < 4; n++)
#pragma unroll
            for (int r = 0; r < 4; r++) {
                float p = __expf(sc[n][r] - m_r[r]);
                sc[n][r] = p;
                ps[r] += p;
            }
#pragma unroll
        for (int off = 1; off < 16; off <<= 1)
#pragma unroll
            for (int r = 0; r < 4; r++) ps[r] += __shfl_xor(ps[r], off);
#pragma unroll
        for (int r = 0; r < 4; r++) l_r[r] = l_r[r] * al[r] + ps[r];
#pragma unroll
        for (int n2 = 0; n2 < 8; n2++)
#pragma unroll
            for (int r = 0; r < 4; r++) accO[n2][r] *= al[r];
        // P -> LDS (per-wave buffer)
#pragma unroll
        for (int n = 0; n < 4; n++)
#pragma unroll
            for (int r = 0; r < 4; r++)
                Ps[w][lg * 4 + r][n * 16 + lr] = (_Float16)sc[n][r];
        __syncthreads();
        // O += P V
#pragma unroll
        for (int kk = 0; kk < 2; kk++) {
            f16x8 ap = *(const f16x8*)&Ps[w][lr][kk * 32 + lg * 8];
#pragma unroll
            for (int n2 = 0; n2 < 8; n2++) {
                f16x8 bv = *(const f16x8*)&Vs[n2 * 16 + lr][kk * 32 + lg * 8];
                accO[n2] = MFMA(ap, bv, accO[n2]);
            }
        }
    }

    const int b = bh >> 4, h = bh & 15;
#pragma unroll
    for (int r = 0; r < 4; r++) {
        float inv = 1.0f / l_r[r];
        int q_abs = qt + w * 16 + lg * 4 + r;
        size_t base = (((size_t)b * SEQ + q_abs) * NH + h) * DH;
#pragma unroll
        for (int n2 = 0; n2 < 8; n2++)
            z_ws[base + n2 * 16 + lr] = (_Float16)(accO[n2][r] * inv);
    }
}

// -------------------- output projection: out = Z * W_O + b_O --------------------
__global__ __launch_bounds__(256)
void k_oproj(const _Float16* __restrict__ Z, const _Float16* __restrict__ WOT,
             const float* __restrict__ bO, float* __restrict__ out) {
    __shared__ __align__(16) _Float16 At[128][72];
    __shared__ __align__(16) _Float16 Bt[128][72];
    const int m0 = blockIdx.x * 128, n0 = blockIdx.y * 128;
    const int tid = threadIdx.x;
    const int w = tid >> 6, lane = tid & 63, lg = lane >> 4, lr = lane & 15;

    f32x4 acc[2][8] = {};

    for (int k0 = 0; k0 < DM; k0 += 64) {
        __syncthreads();
#pragma unroll
        for (int i = 0; i < 4; i++) {
            int cid = i * 256 + tid;
            int row = cid >> 3, k8 = (cid & 7) * 8;
            *(f16x8*)&At[row][k8] = *(const f16x8*)(Z + (size_t)(m0 + row) * DM + k0 + k8);
        }
#pragma unroll
        for (int i = 0; i < 4; i++) {
            int cid = i * 256 + tid;
            int c = cid >> 3, k8 = (cid & 7) * 8;
            *(f16x8*)&Bt[c][k8] = *(const f16x8*)(WOT + (size_t)(n0 + c) * DM + k0 + k8);
        }
        __syncthreads();
#pragma unroll
        for (int kk = 0; kk < 2; kk++) {
            f16x8 a[2], b[8];
#pragma unroll
            for (int m = 0; m < 2; m++) a[m] = *(const f16x8*)&At[w * 32 + m * 16 + lr][kk * 32 + lg * 8];
#pragma unroll
            for (int n = 0; n < 8; n++) b[n] = *(const f16x8*)&Bt[n * 16 + lr][kk * 32 + lg * 8];
#pragma unroll
            for (int m = 0; m < 2; m++)
#pragma unroll
                for (int n = 0; n < 8; n++)
                    acc[m][n] = MFMA(a[m], b[n], acc[m][n]);
        }
    }

    float bo[8];
#pragma unroll
    for (int n = 0; n < 8; n++) bo[n] = bO[n0 + n * 16 + lr];
#pragma unroll
    for (int m = 0; m < 2; m++)
#pragma unroll
        for (int r = 0; r < 4; r++) {
            int row = m0 + w * 32 + m * 16 + lg * 4 + r;
#pragma unroll
            for (int n = 0; n < 8; n++)
                out[(size_t)row * DM + n0 + n * 16 + lr] = acc[m][n][r] + bo[n];
        }
}

extern "C" void kernel_launch(void* const* d_in, const int* in_sizes, int n_in,
                              void* d_out, int out_size, void* d_ws, size_t ws_size,
                              hipStream_t stream) {
    const float* Xq = (const float*)d_in[0];
    const float* Xk = (const float*)d_in[1];
    const float* Xv = (const float*)d_in[2];
    const float* WQ = (const float*)d_in[3];
    const float* WK = (const float*)d_in[4];
    const float* WV = (const float*)d_in[5];
    const float* WO = (const float*)d_in[6];
    const float* bQ = (const float*)d_in[7];
    const float* bK = (const float*)d_in[8];
    const float* bV = (const float*)d_in[9];
    const float* bO = (const float*)d_in[10];
    float* out = (float*)d_out;

    char* ws = (char*)d_ws;
    float* ct = (float*)ws;                               // SEQ*64 fp32
    float* st = (float*)(ws + (512 << 10));
    _Float16* wtq = (_Float16*)(ws + (1 << 20));
    const size_t WSZ = (size_t)NH * DH * DM;              // 4,194,304
    _Float16* wtk = wtq + WSZ;
    _Float16* wtv = wtk + WSZ;
    _Float16* wot = wtv + WSZ;                            // DM*DM
    _Float16* q_ws = wot + (size_t)DM * DM;
    const size_t QSZ = (size_t)NB * NH * SEQ * DH;        // 8,388,608
    _Float16* k_ws  = q_ws + QSZ;
    _Float16* vt_ws = k_ws + QSZ;
    _Float16* z_ws  = vt_ws + QSZ;

    k_sincos<<<512, 256, 0, stream>>>(ct, st);
    k_transpose<<<dim3(4, 64, 16), dim3(32, 8), 0, stream>>>(WQ, wtq, DM, DH);
    k_transpose<<<dim3(4, 64, 16), dim3(32, 8), 0, stream>>>(WK, wtk, DM, DH);
    k_transpose<<<dim3(4, 64, 16), dim3(32, 8), 0, stream>>>(WV, wtv, DM, DH);
    k_transpose<<<dim3(64, 64, 1), dim3(32, 8), 0, stream>>>(WO, wot, DM, DM);
    k_proj<<<dim3(32, NH, 3), 256, 0, stream>>>(Xq, Xk, Xv, wtq, wtk, wtv,
                                                bQ, bK, bV, q_ws, k_ws, vt_ws, ct, st);
    k_attn<<<dim3(32, 32), 256, 0, stream>>>(q_ws, k_ws, vt_ws, z_ws);
    k_oproj<<<dim3(32, NH), 256, 0, stream>>>(z_ws, wot, bO, out);

    (void)in_sizes; (void)n_in; (void)out_size; (void)ws_size;
}

// Round 2
// 569.236 us; speedup vs baseline: 1.0738x; 1.0738x over previous
//
#include <hip/hip_runtime.h>
#include <math.h>

#define DM   2048
#define NH   16
#define DH   128
#define SEQ  2048
#define NB   2

typedef _Float16 f16x8 __attribute__((ext_vector_type(8)));
typedef float    f32x4 __attribute__((ext_vector_type(4)));

#define MFMA(a, b, c) __builtin_amdgcn_mfma_f32_16x16x32_f16((a), (b), (c), 0, 0, 0)

__device__ __forceinline__ void gload16(const _Float16* g, _Float16* lds) {
    __builtin_amdgcn_global_load_lds(
        (const __attribute__((address_space(1))) void*)g,
        (__attribute__((address_space(3))) void*)lds, 16, 0, 0);
}

// -------------------- RoPE sin/cos table: [SEQ][64] each --------------------
__global__ void k_sincos(float* __restrict__ ct, float* __restrict__ st) {
    int idx = blockIdx.x * blockDim.x + threadIdx.x;   // SEQ*64 = 131072
    int p = idx >> 6, i = idx & 63;
    float inv_freq = expf(-(float)i * (9.210340371976184f / 64.0f));
    float a = (float)p * inv_freq;
    float s, c;
    sincosf(a, &s, &c);
    ct[idx] = c;
    st[idx] = s;
}

// -------------------- fp32 -> fp16 bulk convert (X inputs) --------------------
__global__ __launch_bounds__(256)
void k_cvt(const float* __restrict__ a, const float* __restrict__ b, const float* __restrict__ c,
           _Float16* __restrict__ oa, _Float16* __restrict__ ob, _Float16* __restrict__ oc) {
    const float* s = (blockIdx.y == 0) ? a : (blockIdx.y == 1) ? b : c;
    _Float16* o = (blockIdx.y == 0) ? oa : (blockIdx.y == 1) ? ob : oc;
    const int n8 = (NB * SEQ * DM) / 8;   // 1,048,576
    for (int i = blockIdx.x * blockDim.x + threadIdx.x; i < n8; i += gridDim.x * blockDim.x) {
        float4 u = ((const float4*)s)[2 * i];
        float4 v = ((const float4*)s)[2 * i + 1];
        f16x8 pk;
        pk[0] = (_Float16)u.x; pk[1] = (_Float16)u.y; pk[2] = (_Float16)u.z; pk[3] = (_Float16)u.w;
        pk[4] = (_Float16)v.x; pk[5] = (_Float16)v.y; pk[6] = (_Float16)v.z; pk[7] = (_Float16)v.w;
        ((f16x8*)o)[i] = pk;
    }
}

// ---------- tiled transpose fp32 [batch][R][C] -> fp16 [batch][C][R] ----------
__global__ void k_transpose(const float* __restrict__ in, _Float16* __restrict__ out,
                            int R, int C) {
    __shared__ float tile[32][33];
    size_t base = (size_t)blockIdx.z * (size_t)R * (size_t)C;
    int c0 = blockIdx.x * 32, r0 = blockIdx.y * 32;
    int tx = threadIdx.x, ty = threadIdx.y;   // 32 x 8
#pragma unroll
    for (int i = 0; i < 4; i++)
        tile[ty + i * 8][tx] = in[base + (size_t)(r0 + ty + i * 8) * C + c0 + tx];
    __syncthreads();
#pragma unroll
    for (int i = 0; i < 4; i++)
        out[base + (size_t)(c0 + ty + i * 8) * R + r0 + tx] = (_Float16)tile[tx][ty + i * 8];
}

// -------------------- QKV projection + bias + RoPE + scale --------------------
// z=0: Q (rope+scale), z=1: K (rope), z=2: V (written transposed [B,H,D,S])
// A (X, fp16) staged via global_load_lds; B^T (per-head W^T, fp16) likewise.
__global__ __launch_bounds__(256)
void k_proj(const _Float16* __restrict__ Xq, const _Float16* __restrict__ Xk, const _Float16* __restrict__ Xv,
            const _Float16* __restrict__ WTq, const _Float16* __restrict__ WTk, const _Float16* __restrict__ WTv,
            const float* __restrict__ bQ, const float* __restrict__ bK, const float* __restrict__ bV,
            _Float16* __restrict__ q_out, _Float16* __restrict__ k_out, _Float16* __restrict__ vt_out,
            const float* __restrict__ ct, const float* __restrict__ st) {
    __shared__ __align__(16) _Float16 At[128 * 64];
    __shared__ __align__(16) _Float16 Bt[128 * 64];

    const int z = blockIdx.z;
    const _Float16* X  = (z == 0) ? Xq : (z == 1) ? Xk : Xv;
    const _Float16* WT = (z == 0) ? WTq : (z == 1) ? WTk : WTv;
    const float* bias  = (z == 0) ? bQ : (z == 1) ? bK : bV;
    const int h  = blockIdx.y;
    const int m0 = blockIdx.x * 128;
    const int tid = threadIdx.x;
    const int w = tid >> 6, lane = tid & 63, lg = lane >> 4, lr = lane & 15;

    const _Float16* WTh = WT + (size_t)h * DH * DM;

    f32x4 acc[2][8] = {};

    for (int k0 = 0; k0 < DM; k0 += 64) {
        __syncthreads();
        // stage A (128x64) and B^T (128x64) via global_load_lds, 16B granules
#pragma unroll
        for (int j = 0; j < 4; j++) {
            int c = (w * 4 + j) * 64 + lane;           // 16B-chunk id, 0..1023
            int row = c >> 3, seg = c & 7;
            gload16(X   + (size_t)(m0 + row) * DM + k0 + seg * 8, &At[(w * 4 + j) * 512]);
            gload16(WTh + (size_t)row        * DM + k0 + seg * 8, &Bt[(w * 4 + j) * 512]);
        }
        __syncthreads();
#pragma unroll
        for (int kk = 0; kk < 2; kk++) {
            f16x8 a[2], b[8];
#pragma unroll
            for (int m = 0; m < 2; m++)
                a[m] = *(const f16x8*)&At[(w * 32 + m * 16 + lr) * 64 + kk * 32 + lg * 8];
#pragma unroll
            for (int n = 0; n < 8; n++)
                b[n] = *(const f16x8*)&Bt[(n * 16 + lr) * 64 + kk * 32 + lg * 8];
#pragma unroll
            for (int m = 0; m < 2; m++)
#pragma unroll
                for (int n = 0; n < 8; n++)
                    acc[m][n] = MFMA(a[m], b[n], acc[m][n]);
        }
    }

    float bias_v[8];
#pragma unroll
    for (int n = 0; n < 8; n++) bias_v[n] = bias[h * DH + n * 16 + lr];

    const int bb = m0 >> 11;           // batch index
    const int s_base = (m0 & 2047) + w * 32;

    if (z < 2) {
        _Float16* outp = (z == 0) ? q_out : k_out;
        const float scale = (z == 0) ? 0.08838834764831845f : 1.0f;  // 1/sqrt(128)
#pragma unroll
        for (int m = 0; m < 2; m++) {
#pragma unroll
            for (int r = 0; r < 4; r++) {
                int s = s_base + m * 16 + lg * 4 + r;
                size_t rowbase = ((size_t)(bb * NH + h) * SEQ + s) * DH;
#pragma unroll
                for (int n = 0; n < 4; n++) {
                    int c = n * 16 + lr;                 // < 64
                    float cv = ct[s * 64 + c];
                    float sv = st[s * 64 + c];
                    float x0 = acc[m][n][r]     + bias_v[n];
                    float x1 = acc[m][n + 4][r] + bias_v[n + 4];
                    float y0 = (x0 * cv - x1 * sv) * scale;
                    float y1 = (x1 * cv + x0 * sv) * scale;
                    outp[rowbase + c]      = (_Float16)y0;
                    outp[rowbase + c + 64] = (_Float16)y1;
                }
            }
        }
    } else {
#pragma unroll
        for (int m = 0; m < 2; m++)
#pragma unroll
            for (int r = 0; r < 4; r++) {
                int s = s_base + m * 16 + lg * 4 + r;
#pragma unroll
                for (int n = 0; n < 8; n++) {
                    int d = n * 16 + lr;
                    vt_out[((size_t)(bb * NH + h) * DH + d) * SEQ + s] =
                        (_Float16)(acc[m][n][r] + bias_v[n]);
                }
            }
    }
}

// -------------------- causal flash attention --------------------
// q pre-scaled by 1/sqrt(DH). q,k: [B,H,S,D]; v: [B,H,D,S]; z out: [B,S,H,D]
// Qs/Ks: [64][128] fp16, XOR-swizzled; Vs: [128][64] fp16, XOR-swizzled.
#define QK_IDX(r, c) ((r) * 128 + ((c) ^ (((r) & 15) * 8)))
#define V_IDX(d, c)  ((d) * 64  + ((c) ^ (((d) & 7) * 8)))

__global__ __launch_bounds__(256)
void k_attn(const _Float16* __restrict__ q_ws, const _Float16* __restrict__ k_ws,
            const _Float16* __restrict__ vt_ws, _Float16* __restrict__ z_ws) {
    __shared__ __align__(16) _Float16 Qs[64 * 128];
    __shared__ __align__(16) _Float16 Ks[64 * 128];
    __shared__ __align__(16) _Float16 Vs[128 * 64];
    __shared__ __align__(16) _Float16 Ps[4][16][72];

    const int bh = blockIdx.y;          // b*NH + h
    const int qt = blockIdx.x * 64;
    const int tid = threadIdx.x;
    const int w = tid >> 6, lane = tid & 63, lg = lane >> 4, lr = lane & 15;

    const _Float16* Qg = q_ws + (size_t)bh * SEQ * DH;
    const _Float16* Kg = k_ws + (size_t)bh * SEQ * DH;
    const _Float16* Vg = vt_ws + (size_t)bh * DH * SEQ;

#pragma unroll
    for (int i = 0; i < 4; i++) {
        int cid = i * 256 + tid;
        int row = cid >> 4, c8 = (cid & 15) * 8;
        *(f16x8*)&Qs[QK_IDX(row, c8)] = *(const f16x8*)(Qg + (size_t)(qt + row) * DH + c8);
    }

    f32x4 accO[8] = {};
    float m_r[4] = {-1e30f, -1e30f, -1e30f, -1e30f};
    float l_r[4] = {0.f, 0.f, 0.f, 0.f};

    const int ntile = blockIdx.x + 1;
    for (int t = 0; t < ntile; t++) {
        const int kv0 = t * 64;
        __syncthreads();
#pragma unroll
        for (int i = 0; i < 4; i++) {
            int cid = i * 256 + tid;
            int row = cid >> 4, c8 = (cid & 15) * 8;
            *(f16x8*)&Ks[QK_IDX(row, c8)] = *(const f16x8*)(Kg + (size_t)(kv0 + row) * DH + c8);
        }
#pragma unroll
        for (int i = 0; i < 4; i++) {
            int cid = i * 256 + tid;
            int d = cid >> 3, c8 = (cid & 7) * 8;
            *(f16x8*)&Vs[V_IDX(d, c8)] = *(const f16x8*)(Vg + (size_t)d * SEQ + kv0 + c8);
        }
        __syncthreads();

        // S = Q K^T  (wave: 16 q-rows x 64 kv)
        f32x4 sc[4] = {};
#pragma unroll
        for (int kk = 0; kk < 4; kk++) {
            f16x8 aq = *(const f16x8*)&Qs[QK_IDX(w * 16 + lr, kk * 32 + lg * 8)];
#pragma unroll
            for (int n = 0; n < 4; n++) {
                f16x8 bk = *(const f16x8*)&Ks[QK_IDX(n * 16 + lr, kk * 32 + lg * 8)];
                sc[n] = MFMA(aq, bk, sc[n]);
            }
        }
        // causal mask
#pragma unroll
        for (int n = 0; n < 4; n++) {
            int kvc = kv0 + n * 16 + lr;
#pragma unroll
            for (int r = 0; r < 4; r++) {
                int qr = qt + w * 16 + lg * 4 + r;
                if (kvc > qr) sc[n][r] = -1e30f;
            }
        }
        // online softmax (row reductions over 16-lane groups)
        float mt[4];
#pragma unroll
        for (int r = 0; r < 4; r++)
            mt[r] = fmaxf(fmaxf(sc[0][r], sc[1][r]), fmaxf(sc[2][r], sc[3][r]));
#pragma unroll
        for (int off = 1; off < 16; off <<= 1)
#pragma unroll
            for (int r = 0; r < 4; r++) mt[r] = fmaxf(mt[r], __shfl_xor(mt[r], off));
        float al[4];
#pragma unroll
        for (int r = 0; r < 4; r++) {
            float mn = fmaxf(m_r[r], mt[r]);
            al[r] = __expf(m_r[r] - mn);
            m_r[r] = mn;
        }
        float ps[4] = {0.f, 0.f, 0.f, 0.f};
#pragma unroll
        for (int n = 0; n < 4; n++)
#pragma unroll
            for (int r = 0; r < 4; r++) {
                float p = __expf(sc[n][r] - m_r[r]);
                sc[n][r] = p;
                ps[r] += p;
            }
#pragma unroll
        for (int off = 1; off < 16; off <<= 1)
#pragma unroll
            for (int r = 0; r < 4; r++) ps[r] += __shfl_xor(ps[r], off);
#pragma unroll
        for (int r = 0; r < 4; r++) l_r[r] = l_r[r] * al[r] + ps[r];
#pragma unroll
        for (int n2 = 0; n2 < 8; n2++)
#pragma unroll
            for (int r = 0; r < 4; r++) accO[n2][r] *= al[r];
        // P -> LDS (per-wave buffer; same-wave write->read, no barrier needed)
#pragma unroll
        for (int n = 0; n < 4; n++)
#pragma unroll
            for (int r = 0; r < 4; r++)
                Ps[w][lg * 4 + r][n * 16 + lr] = (_Float16)sc[n][r];
        // O += P V
#pragma unroll
        for (int kk = 0; kk < 2; kk++) {
            f16x8 ap = *(const f16x8*)&Ps[w][lr][kk * 32 + lg * 8];
#pragma unroll
            for (int n2 = 0; n2 < 8; n2++) {
                f16x8 bv = *(const f16x8*)&Vs[V_IDX(n2 * 16 + lr, kk * 32 + lg * 8)];
                accO[n2] = MFMA(ap, bv, accO[n2]);
            }
        }
    }

    const int b = bh >> 4, h = bh & 15;
#pragma unroll
    for (int r = 0; r < 4; r++) {
        float inv = 1.0f / l_r[r];
        int q_abs = qt + w * 16 + lg * 4 + r;
        size_t base = (((size_t)b * SEQ + q_abs) * NH + h) * DH;
#pragma unroll
        for (int n2 = 0; n2 < 8; n2++)
            z_ws[base + n2 * 16 + lr] = (_Float16)(accO[n2][r] * inv);
    }
}

// -------------------- output projection: out = Z * W_O + b_O --------------------
__global__ __launch_bounds__(256)
void k_oproj(const _Float16* __restrict__ Z, const _Float16* __restrict__ WOT,
             const float* __restrict__ bO, float* __restrict__ out) {
    __shared__ __align__(16) _Float16 At[128 * 64];
    __shared__ __align__(16) _Float16 Bt[128 * 64];
    const int m0 = blockIdx.x * 128, n0 = blockIdx.y * 128;
    const int tid = threadIdx.x;
    const int w = tid >> 6, lane = tid & 63, lg = lane >> 4, lr = lane & 15;

    f32x4 acc[2][8] = {};

    for (int k0 = 0; k0 < DM; k0 += 64) {
        __syncthreads();
#pragma unroll
        for (int j = 0; j < 4; j++) {
            int c = (w * 4 + j) * 64 + lane;
            int row = c >> 3, seg = c & 7;
            gload16(Z   + (size_t)(m0 + row) * DM + k0 + seg * 8, &At[(w * 4 + j) * 512]);
            gload16(WOT + (size_t)(n0 + row) * DM + k0 + seg * 8, &Bt[(w * 4 + j) * 512]);
        }
        __syncthreads();
#pragma unroll
        for (int kk = 0; kk < 2; kk++) {
            f16x8 a[2], b[8];
#pragma unroll
            for (int m = 0; m < 2; m++)
                a[m] = *(const f16x8*)&At[(w * 32 + m * 16 + lr) * 64 + kk * 32 + lg * 8];
#pragma unroll
            for (int n = 0; n < 8; n++)
                b[n] = *(const f16x8*)&Bt[(n * 16 + lr) * 64 + kk * 32 + lg * 8];
#pragma unroll
            for (int m = 0; m < 2; m++)
#pragma unroll
                for (int n = 0; n < 8; n++)
                    acc[m][n] = MFMA(a[m], b[n], acc[m][n]);
        }
    }

    float bo[8];
#pragma unroll
    for (int n = 0; n < 8; n++) bo[n] = bO[n0 + n * 16 + lr];
#pragma unroll
    for (int m = 0; m < 2; m++)
#pragma unroll
        for (int r = 0; r < 4; r++) {
            int row = m0 + w * 32 + m * 16 + lg * 4 + r;
#pragma unroll
            for (int n = 0; n < 8; n++)
                out[(size_t)row * DM + n0 + n * 16 + lr] = acc[m][n][r] + bo[n];
        }
}

extern "C" void kernel_launch(void* const* d_in, const int* in_sizes, int n_in,
                              void* d_out, int out_size, void* d_ws, size_t ws_size,
                              hipStream_t stream) {
    const float* Xq = (const float*)d_in[0];
    const float* Xk = (const float*)d_in[1];
    const float* Xv = (const float*)d_in[2];
    const float* WQ = (const float*)d_in[3];
    const float* WK = (const float*)d_in[4];
    const float* WV = (const float*)d_in[5];
    const float* WO = (const float*)d_in[6];
    const float* bQ = (const float*)d_in[7];
    const float* bK = (const float*)d_in[8];
    const float* bV = (const float*)d_in[9];
    const float* bO = (const float*)d_in[10];
    float* out = (float*)d_out;

    char* ws = (char*)d_ws;
    float* ct = (float*)ws;                               // SEQ*64 fp32
    float* st = ct + SEQ * 64;
    _Float16* wtq = (_Float16*)(st + SEQ * 64);
    const size_t WSZ = (size_t)NH * DH * DM;              // 4,194,304
    _Float16* wtk = wtq + WSZ;
    _Float16* wtv = wtk + WSZ;
    _Float16* wot = wtv + WSZ;                            // DM*DM
    _Float16* q_ws = wot + (size_t)DM * DM;
    const size_t QSZ = (size_t)NB * NH * SEQ * DH;        // 8,388,608
    _Float16* k_ws  = q_ws + QSZ;
    _Float16* vt_ws = k_ws + QSZ;
    _Float16* z_ws  = vt_ws + QSZ;
    const size_t XSZ = (size_t)NB * SEQ * DM;             // 8,388,608
    _Float16* xq16 = z_ws + QSZ;
    _Float16* xk16 = xq16 + XSZ;
    _Float16* xv16 = xk16 + XSZ;

    k_sincos<<<512, 256, 0, stream>>>(ct, st);
    k_cvt<<<dim3(512, 3), 256, 0, stream>>>(Xq, Xk, Xv, xq16, xk16, xv16);
    k_transpose<<<dim3(4, 64, 16), dim3(32, 8), 0, stream>>>(WQ, wtq, DM, DH);
    k_transpose<<<dim3(4, 64, 16), dim3(32, 8), 0, stream>>>(WK, wtk, DM, DH);
    k_transpose<<<dim3(4, 64, 16), dim3(32, 8), 0, stream>>>(WV, wtv, DM, DH);
    k_transpose<<<dim3(64, 64, 1), dim3(32, 8), 0, stream>>>(WO, wot, DM, DM);
    k_proj<<<dim3(32, NH, 3), 256, 0, stream>>>(xq16, xk16, xv16, wtq, wtk, wtv,
                                                bQ, bK, bV, q_ws, k_ws, vt_ws, ct, st);
    k_attn<<<dim3(32, 32), 256, 0, stream>>>(q_ws, k_ws, vt_ws, z_ws);
    k_oproj<<<dim3(32, NH), 256, 0, stream>>>(z_ws, wot, bO, out);

    (void)in_sizes; (void)n_in; (void)out_size; (void)ws_size;
}

// Round 6
// 553.621 us; speedup vs baseline: 1.1041x; 1.0282x over previous
//
#include <hip/hip_runtime.h>
#include <math.h>

#define DM   2048
#define NH   16
#define DH   128
#define SEQ  2048
#define NB   2

typedef _Float16 f16x8 __attribute__((ext_vector_type(8)));
typedef float    f32x4 __attribute__((ext_vector_type(4)));

#define MFMA(a, b, c) __builtin_amdgcn_mfma_f32_16x16x32_f16((a), (b), (c), 0, 0, 0)

__device__ __forceinline__ void gload16(const _Float16* g, _Float16* lds) {
    __builtin_amdgcn_global_load_lds(
        (const __attribute__((address_space(1))) void*)g,
        (__attribute__((address_space(3))) void*)lds, 16, 0, 0);
}

// -------------------- RoPE sin/cos table: [SEQ][64] each --------------------
__global__ void k_sincos(float* __restrict__ ct, float* __restrict__ st) {
    int idx = blockIdx.x * blockDim.x + threadIdx.x;   // SEQ*64 = 131072
    int p = idx >> 6, i = idx & 63;
    float inv_freq = expf(-(float)i * (9.210340371976184f / 64.0f));
    float a = (float)p * inv_freq;
    float s, c;
    sincosf(a, &s, &c);
    ct[idx] = c;
    st[idx] = s;
}

// -------------------- fp32 -> fp16 bulk convert (X inputs) --------------------
__global__ __launch_bounds__(256)
void k_cvt(const float* __restrict__ a, const float* __restrict__ b, const float* __restrict__ c,
           _Float16* __restrict__ oa, _Float16* __restrict__ ob, _Float16* __restrict__ oc) {
    const float* s = (blockIdx.y == 0) ? a : (blockIdx.y == 1) ? b : c;
    _Float16* o = (blockIdx.y == 0) ? oa : (blockIdx.y == 1) ? ob : oc;
    const int n8 = (NB * SEQ * DM) / 8;   // 1,048,576
    for (int i = blockIdx.x * blockDim.x + threadIdx.x; i < n8; i += gridDim.x * blockDim.x) {
        float4 u = ((const float4*)s)[2 * i];
        float4 v = ((const float4*)s)[2 * i + 1];
        f16x8 pk;
        pk[0] = (_Float16)u.x; pk[1] = (_Float16)u.y; pk[2] = (_Float16)u.z; pk[3] = (_Float16)u.w;
        pk[4] = (_Float16)v.x; pk[5] = (_Float16)v.y; pk[6] = (_Float16)v.z; pk[7] = (_Float16)v.w;
        ((f16x8*)o)[i] = pk;
    }
}

// ---------- tiled transpose fp32 [batch][R][C] -> fp16 [batch][C][R] ----------
__global__ void k_transpose(const float* __restrict__ in, _Float16* __restrict__ out,
                            int R, int C) {
    __shared__ float tile[32][33];
    size_t base = (size_t)blockIdx.z * (size_t)R * (size_t)C;
    int c0 = blockIdx.x * 32, r0 = blockIdx.y * 32;
    int tx = threadIdx.x, ty = threadIdx.y;   // 32 x 8
#pragma unroll
    for (int i = 0; i < 4; i++)
        tile[ty + i * 8][tx] = in[base + (size_t)(r0 + ty + i * 8) * C + c0 + tx];
    __syncthreads();
#pragma unroll
    for (int i = 0; i < 4; i++)
        out[base + (size_t)(c0 + ty + i * 8) * R + r0 + tx] = (_Float16)tile[tx][ty + i * 8];
}

// -------------------- QKV projection + bias + RoPE + scale --------------------
// z=0: Q (rope+scale, exp2-domain), z=1: K (rope), z=2: V (transposed [B,H,D,S])
__global__ __launch_bounds__(256)
void k_proj(const _Float16* __restrict__ Xq, const _Float16* __restrict__ Xk, const _Float16* __restrict__ Xv,
            const _Float16* __restrict__ WTq, const _Float16* __restrict__ WTk, const _Float16* __restrict__ WTv,
            const float* __restrict__ bQ, const float* __restrict__ bK, const float* __restrict__ bV,
            _Float16* __restrict__ q_out, _Float16* __restrict__ k_out, _Float16* __restrict__ vt_out,
            const float* __restrict__ ct, const float* __restrict__ st) {
    __shared__ __align__(16) _Float16 At[128 * 64];
    __shared__ __align__(16) _Float16 Bt[128 * 64];

    const int z = blockIdx.z;
    const _Float16* X  = (z == 0) ? Xq : (z == 1) ? Xk : Xv;
    const _Float16* WT = (z == 0) ? WTq : (z == 1) ? WTk : WTv;
    const float* bias  = (z == 0) ? bQ : (z == 1) ? bK : bV;
    const int h  = blockIdx.y;
    const int m0 = blockIdx.x * 128;
    const int tid = threadIdx.x;
    const int w = tid >> 6, lane = tid & 63, lg = lane >> 4, lr = lane & 15;

    const _Float16* WTh = WT + (size_t)h * DH * DM;

    f32x4 acc[2][8] = {};

    for (int k0 = 0; k0 < DM; k0 += 64) {
        __syncthreads();
#pragma unroll
        for (int j = 0; j < 4; j++) {
            int c = (w * 4 + j) * 64 + lane;           // 16B-chunk id, 0..1023
            int row = c >> 3, seg = c & 7;
            gload16(X   + (size_t)(m0 + row) * DM + k0 + seg * 8, &At[(w * 4 + j) * 512]);
            gload16(WTh + (size_t)row        * DM + k0 + seg * 8, &Bt[(w * 4 + j) * 512]);
        }
        __syncthreads();
#pragma unroll
        for (int kk = 0; kk < 2; kk++) {
            f16x8 a[2], b[8];
#pragma unroll
            for (int m = 0; m < 2; m++)
                a[m] = *(const f16x8*)&At[(w * 32 + m * 16 + lr) * 64 + kk * 32 + lg * 8];
#pragma unroll
            for (int n = 0; n < 8; n++)
                b[n] = *(const f16x8*)&Bt[(n * 16 + lr) * 64 + kk * 32 + lg * 8];
#pragma unroll
            for (int m = 0; m < 2; m++)
#pragma unroll
                for (int n = 0; n < 8; n++)
                    acc[m][n] = MFMA(a[m], b[n], acc[m][n]);
        }
    }

    float bias_v[8];
#pragma unroll
    for (int n = 0; n < 8; n++) bias_v[n] = bias[h * DH + n * 16 + lr];

    const int bb = m0 >> 11;           // batch index
    const int s_base = (m0 & 2047) + w * 32;

    if (z < 2) {
        _Float16* outp = (z == 0) ? q_out : k_out;
        // Q additionally scaled by log2(e) so attention softmax runs in exp2 domain
        const float scale = (z == 0) ? (0.08838834764831845f * 1.4426950408889634f) : 1.0f;
#pragma unroll
        for (int m = 0; m < 2; m++) {
#pragma unroll
            for (int r = 0; r < 4; r++) {
                int s = s_base + m * 16 + lg * 4 + r;
                size_t rowbase = ((size_t)(bb * NH + h) * SEQ + s) * DH;
#pragma unroll
                for (int n = 0; n < 4; n++) {
                    int c = n * 16 + lr;                 // < 64
                    float cv = ct[s * 64 + c];
                    float sv = st[s * 64 + c];
                    float x0 = acc[m][n][r]     + bias_v[n];
                    float x1 = acc[m][n + 4][r] + bias_v[n + 4];
                    float y0 = (x0 * cv - x1 * sv) * scale;
                    float y1 = (x1 * cv + x0 * sv) * scale;
                    outp[rowbase + c]      = (_Float16)y0;
                    outp[rowbase + c + 64] = (_Float16)y1;
                }
            }
        }
    } else {
#pragma unroll
        for (int m = 0; m < 2; m++)
#pragma unroll
            for (int r = 0; r < 4; r++) {
                int s = s_base + m * 16 + lg * 4 + r;
#pragma unroll
                for (int n = 0; n < 8; n++) {
                    int d = n * 16 + lr;
                    vt_out[((size_t)(bb * NH + h) * DH + d) * SEQ + s] =
                        (_Float16)(acc[m][n][r] + bias_v[n]);
                }
            }
    }
}

// -------------------- causal flash attention, paired q-tiles --------------------
// Block handles q-tiles ta=bx and tb=31-bx (shared K/V staging -> uniform work).
// q pre-scaled by log2e/sqrt(DH). q,k: [B,H,S,D]; v: [B,H,D,S]; z out: [B,S,H,D]
#define KS_IDX(r, c) ((r) * 128 + ((c) ^ (((r) & 15) * 8)))
#define V_IDX(d, c)  ((d) * 64  + ((c) ^ (((d) & 7) * 8)))

__global__ __launch_bounds__(256)
void k_attn(const _Float16* __restrict__ q_ws, const _Float16* __restrict__ k_ws,
            const _Float16* __restrict__ vt_ws, _Float16* __restrict__ z_ws) {
    __shared__ __align__(16) _Float16 Ks[64 * 128];
    __shared__ __align__(16) _Float16 Vs[128 * 64];
    __shared__ __align__(16) _Float16 Ps[4][16][72];

    const int bh = blockIdx.y;          // b*NH + h
    const int ta = blockIdx.x;          // 0..15
    const int tb = 31 - ta;             // 16..31
    const int nt = tb + 1;
    const int tid = threadIdx.x;
    const int w = tid >> 6, lane = tid & 63, lg = lane >> 4, lr = lane & 15;

    const _Float16* Qg = q_ws + (size_t)bh * SEQ * DH;
    const _Float16* Kg = k_ws + (size_t)bh * SEQ * DH;
    const _Float16* Vg = vt_ws + (size_t)bh * DH * SEQ;

    // Q-hoist: both tiles' A-fragments in registers
    f16x8 qa[4], qb[4];
#pragma unroll
    for (int kk = 0; kk < 4; kk++) {
        qa[kk] = *(const f16x8*)(Qg + (size_t)(ta * 64 + w * 16 + lr) * DH + kk * 32 + lg * 8);
        qb[kk] = *(const f16x8*)(Qg + (size_t)(tb * 64 + w * 16 + lr) * DH + kk * 32 + lg * 8);
    }

    f32x4 accOa[8] = {}, accOb[8] = {};
    float m_a[4] = {-1e30f, -1e30f, -1e30f, -1e30f};
    float l_a[4] = {0.f, 0.f, 0.f, 0.f};
    float m_b[4] = {-1e30f, -1e30f, -1e30f, -1e30f};
    float l_b[4] = {0.f, 0.f, 0.f, 0.f};

    f16x8 kreg[4], vreg[4];
#define LOADKV(T)                                                                       \
    {                                                                                   \
        int kv0_ = (T) * 64;                                                            \
        _Pragma("unroll")                                                               \
        for (int i = 0; i < 4; i++) {                                                   \
            int cid = i * 256 + tid;                                                    \
            kreg[i] = *(const f16x8*)(Kg + (size_t)(kv0_ + (cid >> 4)) * DH + (cid & 15) * 8); \
            vreg[i] = *(const f16x8*)(Vg + (size_t)(cid >> 3) * SEQ + kv0_ + (cid & 7) * 8);   \
        }                                                                               \
    }

    // one q-tile step: QK^T -> online softmax (exp2 domain) -> PV
    auto process = [&](const f16x8* qf, f32x4* accO, float* m_r, float* l_r,
                       int qtile, int t, int kv0) {
        f32x4 sc[4] = {};
        __builtin_amdgcn_s_setprio(1);
#pragma unroll
        for (int kk = 0; kk < 4; kk++) {
#pragma unroll
            for (int n = 0; n < 4; n++) {
                f16x8 bk = *(const f16x8*)&Ks[KS_IDX(n * 16 + lr, kk * 32 + lg * 8)];
                sc[n] = MFMA(qf[kk], bk, sc[n]);
            }
        }
        __builtin_amdgcn_s_setprio(0);
        if (t == qtile) {   // diagonal tile: causal mask (uniform branch)
#pragma unroll
            for (int n = 0; n < 4; n++) {
                int kvc = kv0 + n * 16 + lr;
#pragma unroll
                for (int r = 0; r < 4; r++) {
                    int qr = qtile * 64 + w * 16 + lg * 4 + r;
                    if (kvc > qr) sc[n][r] = -1e30f;
                }
            }
        }
        float mt[4];
#pragma unroll
        for (int r = 0; r < 4; r++)
            mt[r] = fmaxf(fmaxf(sc[0][r], sc[1][r]), fmaxf(sc[2][r], sc[3][r]));
#pragma unroll
        for (int off = 1; off < 16; off <<= 1)
#pragma unroll
            for (int r = 0; r < 4; r++) mt[r] = fmaxf(mt[r], __shfl_xor(mt[r], off));
        float al[4];
#pragma unroll
        for (int r = 0; r < 4; r++) {
            float mn = fmaxf(m_r[r], mt[r]);
            al[r] = exp2f(m_r[r] - mn);
            m_r[r] = mn;
        }
        float ps[4] = {0.f, 0.f, 0.f, 0.f};
#pragma unroll
        for (int n = 0; n < 4; n++)
#pragma unroll
            for (int r = 0; r < 4; r++) {
                float p = exp2f(sc[n][r] - m_r[r]);
                sc[n][r] = p;
                ps[r] += p;
            }
#pragma unroll
        for (int off = 1; off < 16; off <<= 1)
#pragma unroll
            for (int r = 0; r < 4; r++) ps[r] += __shfl_xor(ps[r], off);
#pragma unroll
        for (int r = 0; r < 4; r++) l_r[r] = l_r[r] * al[r] + ps[r];
#pragma unroll
        for (int n2 = 0; n2 < 8; n2++)
#pragma unroll
            for (int r = 0; r < 4; r++) accO[n2][r] *= al[r];
        // P -> per-wave LDS (same-wave write->read; DS ops are in-order per wave)
#pragma unroll
        for (int n = 0; n < 4; n++)
#pragma unroll
            for (int r = 0; r < 4; r++)
                Ps[w][lg * 4 + r][n * 16 + lr] = (_Float16)sc[n][r];
        __builtin_amdgcn_s_setprio(1);
#pragma unroll
        for (int kk = 0; kk < 2; kk++) {
            f16x8 ap = *(const f16x8*)&Ps[w][lr][kk * 32 + lg * 8];
#pragma unroll
            for (int n2 = 0; n2 < 8; n2++) {
                f16x8 bv = *(const f16x8*)&Vs[V_IDX(n2 * 16 + lr, kk * 32 + lg * 8)];
                accO[n2] = MFMA(ap, bv, accO[n2]);
            }
        }
        __builtin_amdgcn_s_setprio(0);
    };

    LOADKV(0);                              // prologue: issue t=0 loads
    for (int t = 0; t < nt; t++) {
        const int kv0 = t * 64;
        __syncthreads();                    // previous tile's LDS reads done
        // write staged K/V (waits vmcnt automatically), then issue next loads
#pragma unroll
        for (int i = 0; i < 4; i++) {
            int cid = i * 256 + tid;
            *(f16x8*)&Ks[KS_IDX(cid >> 4, (cid & 15) * 8)] = kreg[i];
            *(f16x8*)&Vs[V_IDX(cid >> 3, (cid & 7) * 8)] = vreg[i];
        }
        if (t + 1 < nt) LOADKV(t + 1);      // T14: issue early, land during compute
        __syncthreads();                    // LDS ready

        if (t <= ta) process(qa, accOa, m_a, l_a, ta, t, kv0);
        process(qb, accOb, m_b, l_b, tb, t, kv0);
    }

    const int b = bh >> 4, h = bh & 15;
    auto store = [&](f32x4* accO, float* l_r, int qtile) {
#pragma unroll
        for (int r = 0; r < 4; r++) {
            float inv = 1.0f / l_r[r];
            int q_abs = qtile * 64 + w * 16 + lg * 4 + r;
            size_t base = (((size_t)b * SEQ + q_abs) * NH + h) * DH;
#pragma unroll
            for (int n2 = 0; n2 < 8; n2++)
                z_ws[base + n2 * 16 + lr] = (_Float16)(accO[n2][r] * inv);
        }
    };
    store(accOa, l_a, ta);
    store(accOb, l_b, tb);
}

// -------------------- output projection: out = Z * W_O + b_O --------------------
__global__ __launch_bounds__(256)
void k_oproj(const _Float16* __restrict__ Z, const _Float16* __restrict__ WOT,
             const float* __restrict__ bO, float* __restrict__ out) {
    __shared__ __align__(16) _Float16 At[128 * 64];
    __shared__ __align__(16) _Float16 Bt[128 * 64];
    const int m0 = blockIdx.x * 128, n0 = blockIdx.y * 128;
    const int tid = threadIdx.x;
    const int w = tid >> 6, lane = tid & 63, lg = lane >> 4, lr = lane & 15;

    f32x4 acc[2][8] = {};

    for (int k0 = 0; k0 < DM; k0 += 64) {
        __syncthreads();
#pragma unroll
        for (int j = 0; j < 4; j++) {
            int c = (w * 4 + j) * 64 + lane;
            int row = c >> 3, seg = c & 7;
            gload16(Z   + (size_t)(m0 + row) * DM + k0 + seg * 8, &At[(w * 4 + j) * 512]);
            gload16(WOT + (size_t)(n0 + row) * DM + k0 + seg * 8, &Bt[(w * 4 + j) * 512]);
        }
        __syncthreads();
#pragma unroll
        for (int kk = 0; kk < 2; kk++) {
            f16x8 a[2], b[8];
#pragma unroll
            for (int m = 0; m < 2; m++)
                a[m] = *(const f16x8*)&At[(w * 32 + m * 16 + lr) * 64 + kk * 32 + lg * 8];
#pragma unroll
            for (int n = 0; n < 8; n++)
                b[n] = *(const f16x8*)&Bt[(n * 16 + lr) * 64 + kk * 32 + lg * 8];
#pragma unroll
            for (int m = 0; m < 2; m++)
#pragma unroll
                for (int n = 0; n < 8; n++)
                    acc[m][n] = MFMA(a[m], b[n], acc[m][n]);
        }
    }

    float bo[8];
#pragma unroll
    for (int n = 0; n < 8; n++) bo[n] = bO[n0 + n * 16 + lr];
#pragma unroll
    for (int m = 0; m < 2; m++)
#pragma unroll
        for (int r = 0; r < 4; r++) {
            int row = m0 + w * 32 + m * 16 + lg * 4 + r;
#pragma unroll
            for (int n = 0; n < 8; n++)
                out[(size_t)row * DM + n0 + n * 16 + lr] = acc[m][n][r] + bo[n];
        }
}

extern "C" void kernel_launch(void* const* d_in, const int* in_sizes, int n_in,
                              void* d_out, int out_size, void* d_ws, size_t ws_size,
                              hipStream_t stream) {
    const float* Xq = (const float*)d_in[0];
    const float* Xk = (const float*)d_in[1];
    const float* Xv = (const float*)d_in[2];
    const float* WQ = (const float*)d_in[3];
    const float* WK = (const float*)d_in[4];
    const float* WV = (const float*)d_in[5];
    const float* WO = (const float*)d_in[6];
    const float* bQ = (const float*)d_in[7];
    const float* bK = (const float*)d_in[8];
    const float* bV = (const float*)d_in[9];
    const float* bO = (const float*)d_in[10];
    float* out = (float*)d_out;

    char* ws = (char*)d_ws;
    float* ct = (float*)ws;                               // SEQ*64 fp32
    float* st = ct + SEQ * 64;
    _Float16* wtq = (_Float16*)(st + SEQ * 64);
    const size_t WSZ = (size_t)NH * DH * DM;              // 4,194,304
    _Float16* wtk = wtq + WSZ;
    _Float16* wtv = wtk + WSZ;
    _Float16* wot = wtv + WSZ;                            // DM*DM
    _Float16* q_ws = wot + (size_t)DM * DM;
    const size_t QSZ = (size_t)NB * NH * SEQ * DH;        // 8,388,608
    _Float16* k_ws  = q_ws + QSZ;
    _Float16* vt_ws = k_ws + QSZ;
    _Float16* z_ws  = vt_ws + QSZ;
    const size_t XSZ = (size_t)NB * SEQ * DM;             // 8,388,608
    _Float16* xq16 = z_ws + QSZ;
    _Float16* xk16 = xq16 + XSZ;
    _Float16* xv16 = xk16 + XSZ;

    k_sincos<<<512, 256, 0, stream>>>(ct, st);
    k_cvt<<<dim3(512, 3), 256, 0, stream>>>(Xq, Xk, Xv, xq16, xk16, xv16);
    k_transpose<<<dim3(4, 64, 16), dim3(32, 8), 0, stream>>>(WQ, wtq, DM, DH);
    k_transpose<<<dim3(4, 64, 16), dim3(32, 8), 0, stream>>>(WK, wtk, DM, DH);
    k_transpose<<<dim3(4, 64, 16), dim3(32, 8), 0, stream>>>(WV, wtv, DM, DH);
    k_transpose<<<dim3(64, 64, 1), dim3(32, 8), 0, stream>>>(WO, wot, DM, DM);
    k_proj<<<dim3(32, NH, 3), 256, 0, stream>>>(xq16, xk16, xv16, wtq, wtk, wtv,
                                                bQ, bK, bV, q_ws, k_ws, vt_ws, ct, st);
    k_attn<<<dim3(16, 32), 256, 0, stream>>>(q_ws, k_ws, vt_ws, z_ws);
    k_oproj<<<dim3(32, NH), 256, 0, stream>>>(z_ws, wot, bO, out);

    (void)in_sizes; (void)n_in; (void)out_size; (void)ws_size;
}

// Round 8
// 529.663 us; speedup vs baseline: 1.1540x; 1.0452x over previous
//
#include <hip/hip_runtime.h>
#include <math.h>

#define DM   2048
#define NH   16
#define DH   128
#define SEQ  2048
#define NB   2

typedef _Float16 f16x8 __attribute__((ext_vector_type(8)));
typedef _Float16 f16x4 __attribute__((ext_vector_type(4)));
typedef float    f32x4 __attribute__((ext_vector_type(4)));

#define MFMA(a, b, c) __builtin_amdgcn_mfma_f32_16x16x32_f16((a), (b), (c), 0, 0, 0)

__device__ __forceinline__ void gload16(const _Float16* g, _Float16* lds) {
    __builtin_amdgcn_global_load_lds(
        (const __attribute__((address_space(1))) void*)g,
        (__attribute__((address_space(3))) void*)lds, 16, 0, 0);
}

// -------------------- RoPE sin/cos table: [SEQ][64] each --------------------
__global__ void k_sincos(float* __restrict__ ct, float* __restrict__ st) {
    int idx = blockIdx.x * blockDim.x + threadIdx.x;   // SEQ*64 = 131072
    int p = idx >> 6, i = idx & 63;
    float inv_freq = expf(-(float)i * (9.210340371976184f / 64.0f));
    float a = (float)p * inv_freq;
    float s, c;
    sincosf(a, &s, &c);
    ct[idx] = c;
    st[idx] = s;
}

// -------------------- fp32 -> fp16 bulk convert (X inputs) --------------------
__global__ __launch_bounds__(256)
void k_cvt(const float* __restrict__ a, const float* __restrict__ b, const float* __restrict__ c,
           _Float16* __restrict__ oa, _Float16* __restrict__ ob, _Float16* __restrict__ oc) {
    const float* s = (blockIdx.y == 0) ? a : (blockIdx.y == 1) ? b : c;
    _Float16* o = (blockIdx.y == 0) ? oa : (blockIdx.y == 1) ? ob : oc;
    const int n8 = (NB * SEQ * DM) / 8;   // 1,048,576
    for (int i = blockIdx.x * blockDim.x + threadIdx.x; i < n8; i += gridDim.x * blockDim.x) {
        float4 u = ((const float4*)s)[2 * i];
        float4 v = ((const float4*)s)[2 * i + 1];
        f16x8 pk;
        pk[0] = (_Float16)u.x; pk[1] = (_Float16)u.y; pk[2] = (_Float16)u.z; pk[3] = (_Float16)u.w;
        pk[4] = (_Float16)v.x; pk[5] = (_Float16)v.y; pk[6] = (_Float16)v.z; pk[7] = (_Float16)v.w;
        ((f16x8*)o)[i] = pk;
    }
}

// ---------- tiled transpose fp32 [batch][R][C] -> fp16 [batch][C][R] ----------
__global__ void k_transpose(const float* __restrict__ in, _Float16* __restrict__ out,
                            int R, int C) {
    __shared__ float tile[32][33];
    size_t base = (size_t)blockIdx.z * (size_t)R * (size_t)C;
    int c0 = blockIdx.x * 32, r0 = blockIdx.y * 32;
    int tx = threadIdx.x, ty = threadIdx.y;   // 32 x 8
#pragma unroll
    for (int i = 0; i < 4; i++)
        tile[ty + i * 8][tx] = in[base + (size_t)(r0 + ty + i * 8) * C + c0 + tx];
    __syncthreads();
#pragma unroll
    for (int i = 0; i < 4; i++)
        out[base + (size_t)(c0 + ty + i * 8) * R + r0 + tx] = (_Float16)tile[tx][ty + i * 8];
}

// -------------------- QKV projection + bias + RoPE + scale --------------------
// z=0: Q (rope+scale, exp2-domain), z=1: K (rope), z=2: V (transposed [B,H,D,S])
__global__ __launch_bounds__(256)
void k_proj(const _Float16* __restrict__ Xq, const _Float16* __restrict__ Xk, const _Float16* __restrict__ Xv,
            const _Float16* __restrict__ WTq, const _Float16* __restrict__ WTk, const _Float16* __restrict__ WTv,
            const float* __restrict__ bQ, const float* __restrict__ bK, const float* __restrict__ bV,
            _Float16* __restrict__ q_out, _Float16* __restrict__ k_out, _Float16* __restrict__ vt_out,
            const float* __restrict__ ct, const float* __restrict__ st) {
    __shared__ __align__(16) _Float16 At[128 * 64];
    __shared__ __align__(16) _Float16 Bt[128 * 64];

    const int z = blockIdx.z;
    const _Float16* X  = (z == 0) ? Xq : (z == 1) ? Xk : Xv;
    const _Float16* WT = (z == 0) ? WTq : (z == 1) ? WTk : WTv;
    const float* bias  = (z == 0) ? bQ : (z == 1) ? bK : bV;
    const int h  = blockIdx.y;
    const int m0 = blockIdx.x * 128;
    const int tid = threadIdx.x;
    const int w = tid >> 6, lane = tid & 63, lg = lane >> 4, lr = lane & 15;

    const _Float16* WTh = WT + (size_t)h * DH * DM;

    f32x4 acc[2][8] = {};

    for (int k0 = 0; k0 < DM; k0 += 64) {
        __syncthreads();
#pragma unroll
        for (int j = 0; j < 4; j++) {
            int c = (w * 4 + j) * 64 + lane;           // 16B-chunk id, 0..1023
            int row = c >> 3, seg = c & 7;
            gload16(X   + (size_t)(m0 + row) * DM + k0 + seg * 8, &At[(w * 4 + j) * 512]);
            gload16(WTh + (size_t)row        * DM + k0 + seg * 8, &Bt[(w * 4 + j) * 512]);
        }
        __syncthreads();
#pragma unroll
        for (int kk = 0; kk < 2; kk++) {
            f16x8 a[2], b[8];
#pragma unroll
            for (int m = 0; m < 2; m++)
                a[m] = *(const f16x8*)&At[(w * 32 + m * 16 + lr) * 64 + kk * 32 + lg * 8];
#pragma unroll
            for (int n = 0; n < 8; n++)
                b[n] = *(const f16x8*)&Bt[(n * 16 + lr) * 64 + kk * 32 + lg * 8];
#pragma unroll
            for (int m = 0; m < 2; m++)
#pragma unroll
                for (int n = 0; n < 8; n++)
                    acc[m][n] = MFMA(a[m], b[n], acc[m][n]);
        }
    }

    float bias_v[8];
#pragma unroll
    for (int n = 0; n < 8; n++) bias_v[n] = bias[h * DH + n * 16 + lr];

    const int bb = m0 >> 11;           // batch index
    const int s_base = (m0 & 2047) + w * 32;

    if (z < 2) {
        _Float16* outp = (z == 0) ? q_out : k_out;
        // Q additionally scaled by log2(e) so attention softmax runs in exp2 domain
        const float scale = (z == 0) ? (0.08838834764831845f * 1.4426950408889634f) : 1.0f;
#pragma unroll
        for (int m = 0; m < 2; m++) {
#pragma unroll
            for (int r = 0; r < 4; r++) {
                int s = s_base + m * 16 + lg * 4 + r;
                size_t rowbase = ((size_t)(bb * NH + h) * SEQ + s) * DH;
#pragma unroll
                for (int n = 0; n < 4; n++) {
                    int c = n * 16 + lr;                 // < 64
                    float cv = ct[s * 64 + c];
                    float sv = st[s * 64 + c];
                    float x0 = acc[m][n][r]     + bias_v[n];
                    float x1 = acc[m][n + 4][r] + bias_v[n + 4];
                    float y0 = (x0 * cv - x1 * sv) * scale;
                    float y1 = (x1 * cv + x0 * sv) * scale;
                    outp[rowbase + c]      = (_Float16)y0;
                    outp[rowbase + c + 64] = (_Float16)y1;
                }
            }
        }
    } else {
#pragma unroll
        for (int m = 0; m < 2; m++)
#pragma unroll
            for (int r = 0; r < 4; r++) {
                int s = s_base + m * 16 + lg * 4 + r;
#pragma unroll
                for (int n = 0; n < 8; n++) {
                    int d = n * 16 + lr;
                    vt_out[((size_t)(bb * NH + h) * DH + d) * SEQ + s] =
                        (_Float16)(acc[m][n][r] + bias_v[n]);
                }
            }
    }
}

// -------------------- causal flash attention, paired q-tiles --------------------
// Swapped QK^T: sc = MFMA(K_frag, Q_frag) -> C[kv][q], q lane-local (q = lane&15).
// Softmax row-reduce: 15 in-reg ops + 2 shfl_xor. P staged as 4x ds_write_b64.
// q pre-scaled by log2e/sqrt(DH). q,k: [B,H,S,D]; v: [B,H,D,S]; z out: [B,S,H,D]
#define KS_IDX(r, c) ((r) * 128 + ((c) ^ (((r) & 15) * 8)))
#define V_IDX(d, c)  ((d) * 64  + ((c) ^ (((d) & 7) * 8)))

__global__ __launch_bounds__(256)
void k_attn(const _Float16* __restrict__ q_ws, const _Float16* __restrict__ k_ws,
            const _Float16* __restrict__ vt_ws, _Float16* __restrict__ z_ws) {
    __shared__ __align__(16) _Float16 Ks[64 * 128];
    __shared__ __align__(16) _Float16 Vs[128 * 64];
    __shared__ __align__(16) _Float16 Ps[4][16][72];

    const int bh = blockIdx.y;          // b*NH + h
    const int ta = blockIdx.x;          // 0..15
    const int tb = 31 - ta;             // 16..31
    const int nt = tb + 1;
    const int tid = threadIdx.x;
    const int w = tid >> 6, lane = tid & 63, lg = lane >> 4, lr = lane & 15;

    const _Float16* Qg = q_ws + (size_t)bh * SEQ * DH;
    const _Float16* Kg = k_ws + (size_t)bh * SEQ * DH;
    const _Float16* Vg = vt_ws + (size_t)bh * DH * SEQ;

    // Q-hoist: both tiles' fragments in registers (used as MFMA B-operand)
    f16x8 qa[4], qb[4];
#pragma unroll
    for (int kk = 0; kk < 4; kk++) {
        qa[kk] = *(const f16x8*)(Qg + (size_t)(ta * 64 + w * 16 + lr) * DH + kk * 32 + lg * 8);
        qb[kk] = *(const f16x8*)(Qg + (size_t)(tb * 64 + w * 16 + lr) * DH + kk * 32 + lg * 8);
    }

    f32x4 accOa[8] = {}, accOb[8] = {};
    float m_a = -1e30f, l_a = 0.f;      // per-lane stats for q-row = lane&15
    float m_b = -1e30f, l_b = 0.f;

    f16x8 kreg[4], vreg[4];
#define LOADKV(T)                                                                       \
    {                                                                                   \
        int kv0_ = (T) * 64;                                                            \
        _Pragma("unroll")                                                               \
        for (int i = 0; i < 4; i++) {                                                   \
            int cid = i * 256 + tid;                                                    \
            kreg[i] = *(const f16x8*)(Kg + (size_t)(kv0_ + (cid >> 4)) * DH + (cid & 15) * 8); \
            vreg[i] = *(const f16x8*)(Vg + (size_t)(cid >> 3) * SEQ + kv0_ + (cid & 7) * 8);   \
        }                                                                               \
    }

    const int sq = (lane >> 4) << 2;    // base src-lane for stats transfer

    // one q-tile step: swapped QK^T -> lane-local softmax (exp2) -> PV
    auto process = [&](const f16x8* qf, f32x4* accO, float& m_s, float& l_s,
                       int qtile, int t, int kv0) {
        f32x4 sc[4] = {};
        __builtin_amdgcn_s_setprio(1);
#pragma unroll
        for (int kk = 0; kk < 4; kk++) {
#pragma unroll
            for (int n = 0; n < 4; n++) {
                f16x8 bk = *(const f16x8*)&Ks[KS_IDX(n * 16 + lr, kk * 32 + lg * 8)];
                sc[n] = MFMA(bk, qf[kk], sc[n]);   // C[kv][q]: kv=n*16+lg*4+r, q=lr
            }
        }
        __builtin_amdgcn_s_setprio(0);
        const int qr = qtile * 64 + w * 16 + lr;
        if (t == qtile) {   // diagonal tile: causal mask
#pragma unroll
            for (int n = 0; n < 4; n++)
#pragma unroll
                for (int r = 0; r < 4; r++)
                    if (kv0 + n * 16 + lg * 4 + r > qr) sc[n][r] = -1e30f;
        }
        // row max over this lane's 16 kv values (tree), then across lg groups
        float mx[4];
#pragma unroll
        for (int n = 0; n < 4; n++)
            mx[n] = fmaxf(fmaxf(sc[n][0], sc[n][1]), fmaxf(sc[n][2], sc[n][3]));
        float mt = fmaxf(fmaxf(mx[0], mx[1]), fmaxf(mx[2], mx[3]));
        mt = fmaxf(mt, __shfl_xor(mt, 16));
        mt = fmaxf(mt, __shfl_xor(mt, 32));
        float mn = fmaxf(m_s, mt);
        float al = exp2f(m_s - mn);
        m_s = mn;
        float pssum[4];
#pragma unroll
        for (int n = 0; n < 4; n++) {
#pragma unroll
            for (int r = 0; r < 4; r++) sc[n][r] = exp2f(sc[n][r] - mn);
            pssum[n] = (sc[n][0] + sc[n][1]) + (sc[n][2] + sc[n][3]);
        }
        float ps = (pssum[0] + pssum[1]) + (pssum[2] + pssum[3]);
        ps += __shfl_xor(ps, 16);
        ps += __shfl_xor(ps, 32);
        l_s = l_s * al + ps;
        // transfer alpha to accumulator layout (row q = lg*4+r)
        float alr[4];
#pragma unroll
        for (int r = 0; r < 4; r++) alr[r] = __shfl(al, sq + r);
#pragma unroll
        for (int n2 = 0; n2 < 8; n2++)
#pragma unroll
            for (int r = 0; r < 4; r++) accO[n2][r] *= alr[r];
        // P -> per-wave LDS: 4 contiguous kv-halves per lane = ds_write_b64 x4
#pragma unroll
        for (int n = 0; n < 4; n++) {
            f16x4 h4;
            h4[0] = (_Float16)sc[n][0]; h4[1] = (_Float16)sc[n][1];
            h4[2] = (_Float16)sc[n][2]; h4[3] = (_Float16)sc[n][3];
            *(f16x4*)&Ps[w][lr][n * 16 + lg * 4] = h4;
        }
        __builtin_amdgcn_s_setprio(1);
#pragma unroll
        for (int kk = 0; kk < 2; kk++) {
            f16x8 ap = *(const f16x8*)&Ps[w][lr][kk * 32 + lg * 8];
#pragma unroll
            for (int n2 = 0; n2 < 8; n2++) {
                f16x8 bv = *(const f16x8*)&Vs[V_IDX(n2 * 16 + lr, kk * 32 + lg * 8)];
                accO[n2] = MFMA(ap, bv, accO[n2]);
            }
        }
        __builtin_amdgcn_s_setprio(0);
    };

    LOADKV(0);                              // prologue: issue t=0 loads
    for (int t = 0; t < nt; t++) {
        const int kv0 = t * 64;
        __syncthreads();                    // previous tile's LDS reads done
        // write staged K/V (waits vmcnt automatically), then issue next loads
#pragma unroll
        for (int i = 0; i < 4; i++) {
            int cid = i * 256 + tid;
            *(f16x8*)&Ks[KS_IDX(cid >> 4, (cid & 15) * 8)] = kreg[i];
            *(f16x8*)&Vs[V_IDX(cid >> 3, (cid & 7) * 8)] = vreg[i];
        }
        if (t + 1 < nt) LOADKV(t + 1);      // T14: issue early, land during compute
        __syncthreads();                    // LDS ready

        if (t <= ta) process(qa, accOa, m_a, l_a, ta, t, kv0);
        process(qb, accOb, m_b, l_b, tb, t, kv0);
    }

    const int b = bh >> 4, h = bh & 15;
    auto store = [&](f32x4* accO, float l_s, int qtile) {
#pragma unroll
        for (int r = 0; r < 4; r++) {
            float lv = __shfl(l_s, sq + r);
            float inv = 1.0f / lv;
            int q_abs = qtile * 64 + w * 16 + lg * 4 + r;
            size_t base = (((size_t)b * SEQ + q_abs) * NH + h) * DH;
#pragma unroll
            for (int n2 = 0; n2 < 8; n2++)
                z_ws[base + n2 * 16 + lr] = (_Float16)(accO[n2][r] * inv);
        }
    };
    store(accOa, l_a, ta);
    store(accOb, l_b, tb);
}

// -------------------- output projection: out = Z * W_O + b_O --------------------
__global__ __launch_bounds__(256)
void k_oproj(const _Float16* __restrict__ Z, const _Float16* __restrict__ WOT,
             const float* __restrict__ bO, float* __restrict__ out) {
    __shared__ __align__(16) _Float16 At[128 * 64];
    __shared__ __align__(16) _Float16 Bt[128 * 64];
    const int m0 = blockIdx.x * 128, n0 = blockIdx.y * 128;
    const int tid = threadIdx.x;
    const int w = tid >> 6, lane = tid & 63, lg = lane >> 4, lr = lane & 15;

    f32x4 acc[2][8] = {};

    for (int k0 = 0; k0 < DM; k0 += 64) {
        __syncthreads();
#pragma unroll
        for (int j = 0; j < 4; j++) {
            int c = (w * 4 + j) * 64 + lane;
            int row = c >> 3, seg = c & 7;
            gload16(Z   + (size_t)(m0 + row) * DM + k0 + seg * 8, &At[(w * 4 + j) * 512]);
            gload16(WOT + (size_t)(n0 + row) * DM + k0 + seg * 8, &Bt[(w * 4 + j) * 512]);
        }
        __syncthreads();
#pragma unroll
        for (int kk = 0; kk < 2; kk++) {
            f16x8 a[2], b[8];
#pragma unroll
            for (int m = 0; m < 2; m++)
                a[m] = *(const f16x8*)&At[(w * 32 + m * 16 + lr) * 64 + kk * 32 + lg * 8];
#pragma unroll
            for (int n = 0; n < 8; n++)
                b[n] = *(const f16x8*)&Bt[(n * 16 + lr) * 64 + kk * 32 + lg * 8];
#pragma unroll
            for (int m = 0; m < 2; m++)
#pragma unroll
                for (int n = 0; n < 8; n++)
                    acc[m][n] = MFMA(a[m], b[n], acc[m][n]);
        }
    }

    float bo[8];
#pragma unroll
    for (int n = 0; n < 8; n++) bo[n] = bO[n0 + n * 16 + lr];
#pragma unroll
    for (int m = 0; m < 2; m++)
#pragma unroll
        for (int r = 0; r < 4; r++) {
            int row = m0 + w * 32 + m * 16 + lg * 4 + r;
#pragma unroll
            for (int n = 0; n < 8; n++)
                out[(size_t)row * DM + n0 + n * 16 + lr] = acc[m][n][r] + bo[n];
        }
}

extern "C" void kernel_launch(void* const* d_in, const int* in_sizes, int n_in,
                              void* d_out, int out_size, void* d_ws, size_t ws_size,
                              hipStream_t stream) {
    const float* Xq = (const float*)d_in[0];
    const float* Xk = (const float*)d_in[1];
    const float* Xv = (const float*)d_in[2];
    const float* WQ = (const float*)d_in[3];
    const float* WK = (const float*)d_in[4];
    const float* WV = (const float*)d_in[5];
    const float* WO = (const float*)d_in[6];
    const float* bQ = (const float*)d_in[7];
    const float* bK = (const float*)d_in[8];
    const float* bV = (const float*)d_in[9];
    const float* bO = (const float*)d_in[10];
    float* out = (float*)d_out;

    char* ws = (char*)d_ws;
    float* ct = (float*)ws;                               // SEQ*64 fp32
    float* st = ct + SEQ * 64;
    _Float16* wtq = (_Float16*)(st + SEQ * 64);
    const size_t WSZ = (size_t)NH * DH * DM;              // 4,194,304
    _Float16* wtk = wtq + WSZ;
    _Float16* wtv = wtk + WSZ;
    _Float16* wot = wtv + WSZ;                            // DM*DM
    _Float16* q_ws = wot + (size_t)DM * DM;
    const size_t QSZ = (size_t)NB * NH * SEQ * DH;        // 8,388,608
    _Float16* k_ws  = q_ws + QSZ;
    _Float16* vt_ws = k_ws + QSZ;
    _Float16* z_ws  = vt_ws + QSZ;
    const size_t XSZ = (size_t)NB * SEQ * DM;             // 8,388,608
    _Float16* xq16 = z_ws + QSZ;
    _Float16* xk16 = xq16 + XSZ;
    _Float16* xv16 = xk16 + XSZ;

    k_sincos<<<512, 256, 0, stream>>>(ct, st);
    k_cvt<<<dim3(512, 3), 256, 0, stream>>>(Xq, Xk, Xv, xq16, xk16, xv16);
    k_transpose<<<dim3(4, 64, 16), dim3(32, 8), 0, stream>>>(WQ, wtq, DM, DH);
    k_transpose<<<dim3(4, 64, 16), dim3(32, 8), 0, stream>>>(WK, wtk, DM, DH);
    k_transpose<<<dim3(4, 64, 16), dim3(32, 8), 0, stream>>>(WV, wtv, DM, DH);
    k_transpose<<<dim3(64, 64, 1), dim3(32, 8), 0, stream>>>(WO, wot, DM, DM);
    k_proj<<<dim3(32, NH, 3), 256, 0, stream>>>(xq16, xk16, xv16, wtq, wtk, wtv,
                                                bQ, bK, bV, q_ws, k_ws, vt_ws, ct, st);
    k_attn<<<dim3(16, 32), 256, 0, stream>>>(q_ws, k_ws, vt_ws, z_ws);
    k_oproj<<<dim3(32, NH), 256, 0, stream>>>(z_ws, wot, bO, out);

    (void)in_sizes; (void)n_in; (void)out_size; (void)ws_size;
}

// Round 9
// 496.877 us; speedup vs baseline: 1.2302x; 1.0660x over previous
//
#include <hip/hip_runtime.h>
#include <math.h>

#define DM   2048
#define NH   16
#define DH   128
#define SEQ  2048
#define NB   2

typedef _Float16 f16x8 __attribute__((ext_vector_type(8)));
typedef _Float16 f16x4 __attribute__((ext_vector_type(4)));
typedef float    f32x4 __attribute__((ext_vector_type(4)));

#define MFMA(a, b, c) __builtin_amdgcn_mfma_f32_16x16x32_f16((a), (b), (c), 0, 0, 0)

__device__ __forceinline__ void gload16(const _Float16* g, _Float16* lds) {
    __builtin_amdgcn_global_load_lds(
        (const __attribute__((address_space(1))) void*)g,
        (__attribute__((address_space(3))) void*)lds, 16, 0, 0);
}

// -------------------- RoPE sin/cos table: [SEQ][64] each --------------------
__global__ void k_sincos(float* __restrict__ ct, float* __restrict__ st) {
    int idx = blockIdx.x * blockDim.x + threadIdx.x;   // SEQ*64 = 131072
    int p = idx >> 6, i = idx & 63;
    float inv_freq = expf(-(float)i * (9.210340371976184f / 64.0f));
    float a = (float)p * inv_freq;
    float s, c;
    sincosf(a, &s, &c);
    ct[idx] = c;
    st[idx] = s;
}

// -------------------- fp32 -> fp16 bulk convert (X inputs) --------------------
__global__ __launch_bounds__(256)
void k_cvt(const float* __restrict__ a, const float* __restrict__ b, const float* __restrict__ c,
           _Float16* __restrict__ oa, _Float16* __restrict__ ob, _Float16* __restrict__ oc) {
    const float* s = (blockIdx.y == 0) ? a : (blockIdx.y == 1) ? b : c;
    _Float16* o = (blockIdx.y == 0) ? oa : (blockIdx.y == 1) ? ob : oc;
    const int n8 = (NB * SEQ * DM) / 8;   // 1,048,576
    for (int i = blockIdx.x * blockDim.x + threadIdx.x; i < n8; i += gridDim.x * blockDim.x) {
        float4 u = ((const float4*)s)[2 * i];
        float4 v = ((const float4*)s)[2 * i + 1];
        f16x8 pk;
        pk[0] = (_Float16)u.x; pk[1] = (_Float16)u.y; pk[2] = (_Float16)u.z; pk[3] = (_Float16)u.w;
        pk[4] = (_Float16)v.x; pk[5] = (_Float16)v.y; pk[6] = (_Float16)v.z; pk[7] = (_Float16)v.w;
        ((f16x8*)o)[i] = pk;
    }
}

// ---------- tiled transpose fp32 [batch][R][C] -> fp16 [batch][C][R] ----------
__global__ void k_transpose(const float* __restrict__ in, _Float16* __restrict__ out,
                            int R, int C) {
    __shared__ float tile[32][33];
    size_t base = (size_t)blockIdx.z * (size_t)R * (size_t)C;
    int c0 = blockIdx.x * 32, r0 = blockIdx.y * 32;
    int tx = threadIdx.x, ty = threadIdx.y;   // 32 x 8
#pragma unroll
    for (int i = 0; i < 4; i++)
        tile[ty + i * 8][tx] = in[base + (size_t)(r0 + ty + i * 8) * C + c0 + tx];
    __syncthreads();
#pragma unroll
    for (int i = 0; i < 4; i++)
        out[base + (size_t)(c0 + ty + i * 8) * R + r0 + tx] = (_Float16)tile[tx][ty + i * 8];
}

// ==================== shared GEMM helpers (m97 geometry + T2 swizzle) ========
// LDS tile [128 rows][8 colgroups of 8 f16]; stored slot (row, s) holds global
// colgroup s ^ (row&7). global_load_lds dest stays linear (rule 21): the
// inverse swizzle is applied to the per-lane GLOBAL source address; ds_read
// applies the same XOR. 16-way bank conflict -> 2-way (free).
#define SWZ(row, cg) (((row) * 64) + ((((cg) ^ ((row) & 7))) << 3))

// -------------------- QKV projection + bias + RoPE + scale --------------------
// z=0: Q (rope+scale, exp2-domain), z=1: K (rope), z=2: V (transposed [B,H,D,S])
// 4 waves x (64 rows x {32+32 cols}); wave cols = wc..wc+31 and wc+64..wc+95 so
// RoPE pairs (c, c+64) live in the same lane (acc n and n+2).
__global__ __launch_bounds__(256)
void k_proj(const _Float16* __restrict__ Xq, const _Float16* __restrict__ Xk, const _Float16* __restrict__ Xv,
            const _Float16* __restrict__ WTq, const _Float16* __restrict__ WTk, const _Float16* __restrict__ WTv,
            const float* __restrict__ bQ, const float* __restrict__ bK, const float* __restrict__ bV,
            _Float16* __restrict__ q_out, _Float16* __restrict__ k_out, _Float16* __restrict__ vt_out,
            const float* __restrict__ ct, const float* __restrict__ st) {
    __shared__ __align__(16) _Float16 At[128 * 64];
    __shared__ __align__(16) _Float16 Bt[128 * 64];

    const int z = blockIdx.z;
    const _Float16* X  = (z == 0) ? Xq : (z == 1) ? Xk : Xv;
    const _Float16* WT = (z == 0) ? WTq : (z == 1) ? WTk : WTv;
    const float* bias  = (z == 0) ? bQ : (z == 1) ? bK : bV;
    const int h  = blockIdx.y;
    const int m0 = blockIdx.x * 128;
    const int tid = threadIdx.x;
    const int w = tid >> 6, lane = tid & 63, lg = lane >> 4, lr = lane & 15;
    const int wr = (w >> 1) * 64;       // wave row base
    const int wc = (w & 1) * 32;        // wave col base (low half)

    const _Float16* WTh = WT + (size_t)h * DH * DM;

    f32x4 acc[4][4] = {};

    for (int k0 = 0; k0 < DM; k0 += 64) {
        __syncthreads();
#pragma unroll
        for (int j = 0; j < 4; j++) {
            int c = (w * 4 + j) * 64 + lane;   // 16B-chunk id, 0..1023
            int row = c >> 3;
            int gcg = (c & 7) ^ (row & 7);     // inverse-swizzled source colgroup
            gload16(X   + (size_t)(m0 + row) * DM + k0 + gcg * 8, &At[(w * 4 + j) * 512]);
            gload16(WTh + (size_t)row        * DM + k0 + gcg * 8, &Bt[(w * 4 + j) * 512]);
        }
        __syncthreads();
#pragma unroll
        for (int kk = 0; kk < 2; kk++) {
            f16x8 a[4], b[4];
#pragma unroll
            for (int m = 0; m < 4; m++) {
                int row = wr + m * 16 + lr;
                a[m] = *(const f16x8*)&At[SWZ(row, kk * 4 + lg)];
            }
#pragma unroll
            for (int n = 0; n < 4; n++) {
                int brow = wc + (n & 1) * 16 + (n >> 1) * 64 + lr;
                b[n] = *(const f16x8*)&Bt[SWZ(brow, kk * 4 + lg)];
            }
#pragma unroll
            for (int m = 0; m < 4; m++)
#pragma unroll
                for (int n = 0; n < 4; n++)
                    acc[m][n] = MFMA(a[m], b[n], acc[m][n]);
        }
    }

    int coln[4];
#pragma unroll
    for (int n = 0; n < 4; n++) coln[n] = wc + (n & 1) * 16 + (n >> 1) * 64 + lr;
    float bias_v[4];
#pragma unroll
    for (int n = 0; n < 4; n++) bias_v[n] = bias[h * DH + coln[n]];

    const int bb = m0 >> 11;              // batch index
    const int s_base = (m0 & 2047) + wr;

    if (z < 2) {
        _Float16* outp = (z == 0) ? q_out : k_out;
        // Q additionally scaled by log2(e) so attention softmax runs in exp2 domain
        const float scale = (z == 0) ? (0.08838834764831845f * 1.4426950408889634f) : 1.0f;
#pragma unroll
        for (int m = 0; m < 4; m++) {
#pragma unroll
            for (int r = 0; r < 4; r++) {
                int s = s_base + m * 16 + lg * 4 + r;
                size_t rowbase = ((size_t)(bb * NH + h) * SEQ + s) * DH;
#pragma unroll
                for (int n = 0; n < 2; n++) {
                    int c = coln[n];                 // < 64
                    float cv = ct[s * 64 + c];
                    float sv = st[s * 64 + c];
                    float x0 = acc[m][n][r]     + bias_v[n];
                    float x1 = acc[m][n + 2][r] + bias_v[n + 2];
                    float y0 = (x0 * cv - x1 * sv) * scale;
                    float y1 = (x1 * cv + x0 * sv) * scale;
                    outp[rowbase + c]      = (_Float16)y0;
                    outp[rowbase + c + 64] = (_Float16)y1;
                }
            }
        }
    } else {
#pragma unroll
        for (int m = 0; m < 4; m++)
#pragma unroll
            for (int r = 0; r < 4; r++) {
                int s = s_base + m * 16 + lg * 4 + r;
#pragma unroll
                for (int n = 0; n < 4; n++) {
                    int d = coln[n];
                    vt_out[((size_t)(bb * NH + h) * DH + d) * SEQ + s] =
                        (_Float16)(acc[m][n][r] + bias_v[n]);
                }
            }
    }
}

// -------------------- causal flash attention, paired q-tiles --------------------
// Swapped QK^T: sc = MFMA(K_frag, Q_frag) -> C[kv][q], q lane-local (q = lane&15).
// Softmax row-reduce: 15 in-reg ops + 2 shfl_xor. P staged as 4x ds_write_b64.
// q pre-scaled by log2e/sqrt(DH). q,k: [B,H,S,D]; v: [B,H,D,S]; z out: [B,S,H,D]
#define KS_IDX(r, c) ((r) * 128 + ((c) ^ (((r) & 15) * 8)))
#define V_IDX(d, c)  ((d) * 64  + ((c) ^ (((d) & 7) * 8)))

__global__ __launch_bounds__(256)
void k_attn(const _Float16* __restrict__ q_ws, const _Float16* __restrict__ k_ws,
            const _Float16* __restrict__ vt_ws, _Float16* __restrict__ z_ws) {
    __shared__ __align__(16) _Float16 Ks[64 * 128];
    __shared__ __align__(16) _Float16 Vs[128 * 64];
    __shared__ __align__(16) _Float16 Ps[4][16][72];

    const int bh = blockIdx.y;          // b*NH + h
    const int ta = blockIdx.x;          // 0..15
    const int tb = 31 - ta;             // 16..31
    const int nt = tb + 1;
    const int tid = threadIdx.x;
    const int w = tid >> 6, lane = tid & 63, lg = lane >> 4, lr = lane & 15;

    const _Float16* Qg = q_ws + (size_t)bh * SEQ * DH;
    const _Float16* Kg = k_ws + (size_t)bh * SEQ * DH;
    const _Float16* Vg = vt_ws + (size_t)bh * DH * SEQ;

    // Q-hoist: both tiles' fragments in registers (used as MFMA B-operand)
    f16x8 qa[4], qb[4];
#pragma unroll
    for (int kk = 0; kk < 4; kk++) {
        qa[kk] = *(const f16x8*)(Qg + (size_t)(ta * 64 + w * 16 + lr) * DH + kk * 32 + lg * 8);
        qb[kk] = *(const f16x8*)(Qg + (size_t)(tb * 64 + w * 16 + lr) * DH + kk * 32 + lg * 8);
    }

    f32x4 accOa[8] = {}, accOb[8] = {};
    float m_a = -1e30f, l_a = 0.f;      // per-lane stats for q-row = lane&15
    float m_b = -1e30f, l_b = 0.f;

    f16x8 kreg[4], vreg[4];
#define LOADKV(T)                                                                       \
    {                                                                                   \
        int kv0_ = (T) * 64;                                                            \
        _Pragma("unroll")                                                               \
        for (int i = 0; i < 4; i++) {                                                   \
            int cid = i * 256 + tid;                                                    \
            kreg[i] = *(const f16x8*)(Kg + (size_t)(kv0_ + (cid >> 4)) * DH + (cid & 15) * 8); \
            vreg[i] = *(const f16x8*)(Vg + (size_t)(cid >> 3) * SEQ + kv0_ + (cid & 7) * 8);   \
        }                                                                               \
    }

    const int sq = (lane >> 4) << 2;    // base src-lane for stats transfer

    // one q-tile step: swapped QK^T -> lane-local softmax (exp2) -> PV
    auto process = [&](const f16x8* qf, f32x4* accO, float& m_s, float& l_s,
                       int qtile, int t, int kv0) {
        f32x4 sc[4] = {};
        __builtin_amdgcn_s_setprio(1);
#pragma unroll
        for (int kk = 0; kk < 4; kk++) {
#pragma unroll
            for (int n = 0; n < 4; n++) {
                f16x8 bk = *(const f16x8*)&Ks[KS_IDX(n * 16 + lr, kk * 32 + lg * 8)];
                sc[n] = MFMA(bk, qf[kk], sc[n]);   // C[kv][q]: kv=n*16+lg*4+r, q=lr
            }
        }
        __builtin_amdgcn_s_setprio(0);
        const int qr = qtile * 64 + w * 16 + lr;
        if (t == qtile) {   // diagonal tile: causal mask
#pragma unroll
            for (int n = 0; n < 4; n++)
#pragma unroll
                for (int r = 0; r < 4; r++)
                    if (kv0 + n * 16 + lg * 4 + r > qr) sc[n][r] = -1e30f;
        }
        // row max over this lane's 16 kv values (tree), then across lg groups
        float mx[4];
#pragma unroll
        for (int n = 0; n < 4; n++)
            mx[n] = fmaxf(fmaxf(sc[n][0], sc[n][1]), fmaxf(sc[n][2], sc[n][3]));
        float mt = fmaxf(fmaxf(mx[0], mx[1]), fmaxf(mx[2], mx[3]));
        mt = fmaxf(mt, __shfl_xor(mt, 16));
        mt = fmaxf(mt, __shfl_xor(mt, 32));
        float mn = fmaxf(m_s, mt);
        float al = exp2f(m_s - mn);
        m_s = mn;
        float pssum[4];
#pragma unroll
        for (int n = 0; n < 4; n++) {
#pragma unroll
            for (int r = 0; r < 4; r++) sc[n][r] = exp2f(sc[n][r] - mn);
            pssum[n] = (sc[n][0] + sc[n][1]) + (sc[n][2] + sc[n][3]);
        }
        float ps = (pssum[0] + pssum[1]) + (pssum[2] + pssum[3]);
        ps += __shfl_xor(ps, 16);
        ps += __shfl_xor(ps, 32);
        l_s = l_s * al + ps;
        // transfer alpha to accumulator layout (row q = lg*4+r)
        float alr[4];
#pragma unroll
        for (int r = 0; r < 4; r++) alr[r] = __shfl(al, sq + r);
#pragma unroll
        for (int n2 = 0; n2 < 8; n2++)
#pragma unroll
            for (int r = 0; r < 4; r++) accO[n2][r] *= alr[r];
        // P -> per-wave LDS: 4 contiguous kv-halves per lane = ds_write_b64 x4
#pragma unroll
        for (int n = 0; n < 4; n++) {
            f16x4 h4;
            h4[0] = (_Float16)sc[n][0]; h4[1] = (_Float16)sc[n][1];
            h4[2] = (_Float16)sc[n][2]; h4[3] = (_Float16)sc[n][3];
            *(f16x4*)&Ps[w][lr][n * 16 + lg * 4] = h4;
        }
        __builtin_amdgcn_s_setprio(1);
#pragma unroll
        for (int kk = 0; kk < 2; kk++) {
            f16x8 ap = *(const f16x8*)&Ps[w][lr][kk * 32 + lg * 8];
#pragma unroll
            for (int n2 = 0; n2 < 8; n2++) {
                f16x8 bv = *(const f16x8*)&Vs[V_IDX(n2 * 16 + lr, kk * 32 + lg * 8)];
                accO[n2] = MFMA(ap, bv, accO[n2]);
            }
        }
        __builtin_amdgcn_s_setprio(0);
    };

    LOADKV(0);                              // prologue: issue t=0 loads
    for (int t = 0; t < nt; t++) {
        const int kv0 = t * 64;
        __syncthreads();                    // previous tile's LDS reads done
        // write staged K/V (waits vmcnt automatically), then issue next loads
#pragma unroll
        for (int i = 0; i < 4; i++) {
            int cid = i * 256 + tid;
            *(f16x8*)&Ks[KS_IDX(cid >> 4, (cid & 15) * 8)] = kreg[i];
            *(f16x8*)&Vs[V_IDX(cid >> 3, (cid & 7) * 8)] = vreg[i];
        }
        if (t + 1 < nt) LOADKV(t + 1);      // T14: issue early, land during compute
        __syncthreads();                    // LDS ready

        if (t <= ta) process(qa, accOa, m_a, l_a, ta, t, kv0);
        process(qb, accOb, m_b, l_b, tb, t, kv0);
    }

    const int b = bh >> 4, h = bh & 15;
    auto store = [&](f32x4* accO, float l_s, int qtile) {
#pragma unroll
        for (int r = 0; r < 4; r++) {
            float lv = __shfl(l_s, sq + r);
            float inv = 1.0f / lv;
            int q_abs = qtile * 64 + w * 16 + lg * 4 + r;
            size_t base = (((size_t)b * SEQ + q_abs) * NH + h) * DH;
#pragma unroll
            for (int n2 = 0; n2 < 8; n2++)
                z_ws[base + n2 * 16 + lr] = (_Float16)(accO[n2][r] * inv);
        }
    };
    store(accOa, l_a, ta);
    store(accOb, l_b, tb);
}

// -------------------- output projection: out = Z * W_O + b_O --------------------
__global__ __launch_bounds__(256)
void k_oproj(const _Float16* __restrict__ Z, const _Float16* __restrict__ WOT,
             const float* __restrict__ bO, float* __restrict__ out) {
    __shared__ __align__(16) _Float16 At[128 * 64];
    __shared__ __align__(16) _Float16 Bt[128 * 64];
    const int m0 = blockIdx.x * 128, n0 = blockIdx.y * 128;
    const int tid = threadIdx.x;
    const int w = tid >> 6, lane = tid & 63, lg = lane >> 4, lr = lane & 15;
    const int wr = (w >> 1) * 64;
    const int wc = (w & 1) * 32;

    f32x4 acc[4][4] = {};

    for (int k0 = 0; k0 < DM; k0 += 64) {
        __syncthreads();
#pragma unroll
        for (int j = 0; j < 4; j++) {
            int c = (w * 4 + j) * 64 + lane;
            int row = c >> 3;
            int gcg = (c & 7) ^ (row & 7);
            gload16(Z   + (size_t)(m0 + row) * DM + k0 + gcg * 8, &At[(w * 4 + j) * 512]);
            gload16(WOT + (size_t)(n0 + row) * DM + k0 + gcg * 8, &Bt[(w * 4 + j) * 512]);
        }
        __syncthreads();
#pragma unroll
        for (int kk = 0; kk < 2; kk++) {
            f16x8 a[4], b[4];
#pragma unroll
            for (int m = 0; m < 4; m++) {
                int row = wr + m * 16 + lr;
                a[m] = *(const f16x8*)&At[SWZ(row, kk * 4 + lg)];
            }
#pragma unroll
            for (int n = 0; n < 4; n++) {
                int brow = wc + (n & 1) * 16 + (n >> 1) * 64 + lr;
                b[n] = *(const f16x8*)&Bt[SWZ(brow, kk * 4 + lg)];
            }
#pragma unroll
            for (int m = 0; m < 4; m++)
#pragma unroll
                for (int n = 0; n < 4; n++)
                    acc[m][n] = MFMA(a[m], b[n], acc[m][n]);
        }
    }

    int coln[4];
#pragma unroll
    for (int n = 0; n < 4; n++) coln[n] = wc + (n & 1) * 16 + (n >> 1) * 64 + lr;
    float bo_v[4];
#pragma unroll
    for (int n = 0; n < 4; n++) bo_v[n] = bO[n0 + coln[n]];
#pragma unroll
    for (int m = 0; m < 4; m++)
#pragma unroll
        for (int r = 0; r < 4; r++) {
            int row = m0 + wr + m * 16 + lg * 4 + r;
#pragma unroll
            for (int n = 0; n < 4; n++)
                out[(size_t)row * DM + n0 + coln[n]] = acc[m][n][r] + bo_v[n];
        }
}

extern "C" void kernel_launch(void* const* d_in, const int* in_sizes, int n_in,
                              void* d_out, int out_size, void* d_ws, size_t ws_size,
                              hipStream_t stream) {
    const float* Xq = (const float*)d_in[0];
    const float* Xk = (const float*)d_in[1];
    const float* Xv = (const float*)d_in[2];
    const float* WQ = (const float*)d_in[3];
    const float* WK = (const float*)d_in[4];
    const float* WV = (const float*)d_in[5];
    const float* WO = (const float*)d_in[6];
    const float* bQ = (const float*)d_in[7];
    const float* bK = (const float*)d_in[8];
    const float* bV = (const float*)d_in[9];
    const float* bO = (const float*)d_in[10];
    float* out = (float*)d_out;

    char* ws = (char*)d_ws;
    float* ct = (float*)ws;                               // SEQ*64 fp32
    float* st = ct + SEQ * 64;
    _Float16* wtq = (_Float16*)(st + SEQ * 64);
    const size_t WSZ = (size_t)NH * DH * DM;              // 4,194,304
    _Float16* wtk = wtq + WSZ;
    _Float16* wtv = wtk + WSZ;
    _Float16* wot = wtv + WSZ;                            // DM*DM
    _Float16* q_ws = wot + (size_t)DM * DM;
    const size_t QSZ = (size_t)NB * NH * SEQ * DH;        // 8,388,608
    _Float16* k_ws  = q_ws + QSZ;
    _Float16* vt_ws = k_ws + QSZ;
    _Float16* z_ws  = vt_ws + QSZ;
    const size_t XSZ = (size_t)NB * SEQ * DM;             // 8,388,608
    _Float16* xq16 = z_ws + QSZ;
    _Float16* xk16 = xq16 + XSZ;
    _Float16* xv16 = xk16 + XSZ;

    k_sincos<<<512, 256, 0, stream>>>(ct, st);
    k_cvt<<<dim3(512, 3), 256, 0, stream>>>(Xq, Xk, Xv, xq16, xk16, xv16);
    k_transpose<<<dim3(4, 64, 16), dim3(32, 8), 0, stream>>>(WQ, wtq, DM, DH);
    k_transpose<<<dim3(4, 64, 16), dim3(32, 8), 0, stream>>>(WK, wtk, DM, DH);
    k_transpose<<<dim3(4, 64, 16), dim3(32, 8), 0, stream>>>(WV, wtv, DM, DH);
    k_transpose<<<dim3(64, 64, 1), dim3(32, 8), 0, stream>>>(WO, wot, DM, DM);
    k_proj<<<dim3(32, NH, 3), 256, 0, stream>>>(xq16, xk16, xv16, wtq, wtk, wtv,
                                                bQ, bK, bV, q_ws, k_ws, vt_ws, ct, st);
    k_attn<<<dim3(16, 32), 256, 0, stream>>>(q_ws, k_ws, vt_ws, z_ws);
    k_oproj<<<dim3(32, NH), 256, 0, stream>>>(z_ws, wot, bO, out);

    (void)in_sizes; (void)n_in; (void)out_size; (void)ws_size;
}